// Round 11
// baseline (924.632 us; speedup 1.0000x reference)
//
#include <hip/hip_runtime.h>
#include <hip/hip_fp16.h>

typedef _Float16 f16;
typedef __attribute__((ext_vector_type(4))) _Float16 f16x4;
typedef __attribute__((ext_vector_type(8))) _Float16 f16x8;
typedef __attribute__((ext_vector_type(4))) float f32x4;

#define S_LEN 2048
#define D_MODEL 1024
#define N_HEADS 16
#define D_K 64
#define BATCH 4

// exp(-8): folded into mask so unnormalized P' = exp(score+rel-8)*mask stays small (f16-safe).
// Common to every unmasked column -> its f16 quantization cancels exactly in P'/sum and PV/sum.
#define EXP_NEG8 3.35462627903e-4f

// lgkmcnt-only barrier: does NOT drain vmcnt, so staged global loads stay in flight across it.
// The "memory" clobber also pins global loads into their issue phase (no sinking).
#define LBAR() do { asm volatile("s_waitcnt lgkmcnt(0)" ::: "memory"); \
                    __builtin_amdgcn_s_barrier(); } while (0)

__device__ __forceinline__ int4 pack8(const float4 a, const float4 b) {
  union { f16 h[8]; int4 i; } u;
  u.h[0] = (f16)a.x; u.h[1] = (f16)a.y; u.h[2] = (f16)a.z; u.h[3] = (f16)a.w;
  u.h[4] = (f16)b.x; u.h[5] = (f16)b.y; u.h[6] = (f16)b.z; u.h[7] = (f16)b.w;
  return u.i;
}

// ---------------- fp32 -> fp16 convert (vectorized) ----------------
__global__ void cvt_f32_f16(const float* __restrict__ src, f16* __restrict__ dst, int n4) {
  int i = blockIdx.x * blockDim.x + threadIdx.x;
  if (i < n4) {
    const float4 v = reinterpret_cast<const float4*>(src)[i];
    f16x4 h;
    h.x = (f16)v.x; h.y = (f16)v.y; h.z = (f16)v.z; h.w = (f16)v.w;
    reinterpret_cast<f16x4*>(dst)[i] = h;
  }
}

// ---------------- weight transpose + convert (batched over 4 weights) ----------------
__global__ void wtrans4(const float* __restrict__ W0, const float* __restrict__ W1,
                        const float* __restrict__ W2, const float* __restrict__ W3,
                        f16* __restrict__ T0, f16* __restrict__ T1, f16* __restrict__ T2,
                        f16* __restrict__ T3) {
  const float* W = blockIdx.z == 0 ? W0 : (blockIdx.z == 1 ? W1 : (blockIdx.z == 2 ? W2 : W3));
  f16* WT = blockIdx.z == 0 ? T0 : (blockIdx.z == 1 ? T1 : (blockIdx.z == 2 ? T2 : T3));
  __shared__ float tile[32][33];
  const int n0 = blockIdx.x * 32, k0 = blockIdx.y * 32;
  const int tx = threadIdx.x, ty = threadIdx.y;  // block (32,8)
#pragma unroll
  for (int i = 0; i < 4; ++i)
    tile[ty + i * 8][tx] = W[(size_t)(k0 + ty + i * 8) * D_MODEL + n0 + tx];
  __syncthreads();
#pragma unroll
  for (int i = 0; i < 4; ++i)
    WT[(size_t)(n0 + ty + i * 8) * D_MODEL + k0 + tx] = (f16)tile[tx][ty + i * 8];
}

// ---------------- GEMM: C[8192][1024] = A @ W + bias, W given as WT[n][k] (f16) ----------------
// AF32: A is fp32 (raw harness input), converted to f16 in-register during staging (L3-resident
// re-reads). Raw-barrier pipelined: one lgkm-only barrier per K-step. MODE 2 swaps MFMA operands
// so the D-tile is transposed in-register -> coalesced V^T stores.
template <int MODE, bool AF32>
__global__ __launch_bounds__(256, 3) void gemm16(const void* __restrict__ Ap, const f16* __restrict__ BT,
                                                 const float* __restrict__ bias, void* __restrict__ outp) {
  __shared__ f16 As[2][128 * 40];
  __shared__ f16 Bs[2][128 * 40];
  const int t = threadIdx.x;
  const int lane = t & 63, wid = t >> 6;
  const int wm = wid >> 1, wn = wid & 1;
  const int lr = lane & 15, lg = lane >> 4;
  const int bm = blockIdx.y * 128, bn = blockIdx.x * 128;

  f32x4 acc[4][4] = {};

  // staging map: rows r0s and r0s+64, 8-element col-group g0
  const int r0s = t >> 2, g0 = (t & 3) * 8;
  const f16* gA0h = (const f16*)Ap + (size_t)(bm + r0s) * 1024 + g0;
  const f16* gA1h = gA0h + (size_t)64 * 1024;
  const float* gA0f = (const float*)Ap + (size_t)(bm + r0s) * 1024 + g0;
  const float* gA1f = gA0f + (size_t)64 * 1024;
  const f16* gB0 = &BT[(size_t)(bn + r0s) * 1024 + g0];
  const f16* gB1 = gB0 + (size_t)64 * 1024;
  const int dst0 = r0s * 40 + g0, dst1 = (r0s + 64) * 40 + g0;

  int4 sB0, sB1;
  int4 sA0h, sA1h;
  float4 sA0a, sA0b, sA1a, sA1b;

  auto GLOAD = [&](int k0) {
    if constexpr (AF32) {
      sA0a = *reinterpret_cast<const float4*>(gA0f + k0);
      sA0b = *reinterpret_cast<const float4*>(gA0f + k0 + 4);
      sA1a = *reinterpret_cast<const float4*>(gA1f + k0);
      sA1b = *reinterpret_cast<const float4*>(gA1f + k0 + 4);
    } else {
      sA0h = *reinterpret_cast<const int4*>(gA0h + k0);
      sA1h = *reinterpret_cast<const int4*>(gA1h + k0);
    }
    sB0 = *reinterpret_cast<const int4*>(gB0 + k0);
    sB1 = *reinterpret_cast<const int4*>(gB1 + k0);
  };
  auto DSW = [&](int bb) {
    if constexpr (AF32) {
      *reinterpret_cast<int4*>(&As[bb][dst0]) = pack8(sA0a, sA0b);
      *reinterpret_cast<int4*>(&As[bb][dst1]) = pack8(sA1a, sA1b);
    } else {
      *reinterpret_cast<int4*>(&As[bb][dst0]) = sA0h;
      *reinterpret_cast<int4*>(&As[bb][dst1]) = sA1h;
    }
    *reinterpret_cast<int4*>(&Bs[bb][dst0]) = sB0;
    *reinterpret_cast<int4*>(&Bs[bb][dst1]) = sB1;
  };
  auto COMPUTE = [&](int bb) {
#pragma unroll
    for (int kk = 0; kk < 2; ++kk) {
      f16x4 af[4], bf[4];
#pragma unroll
      for (int mf = 0; mf < 4; ++mf)
        af[mf] = *reinterpret_cast<const f16x4*>(&As[bb][(wm * 64 + mf * 16 + lr) * 40 + kk * 16 + 4 * lg]);
#pragma unroll
      for (int nf = 0; nf < 4; ++nf)
        bf[nf] = *reinterpret_cast<const f16x4*>(&Bs[bb][(wn * 64 + nf * 16 + lr) * 40 + kk * 16 + 4 * lg]);
#pragma unroll
      for (int mf = 0; mf < 4; ++mf)
#pragma unroll
        for (int nf = 0; nf < 4; ++nf) {
          if (MODE == 2)
            acc[mf][nf] = __builtin_amdgcn_mfma_f32_16x16x16f16(bf[nf], af[mf], acc[mf][nf], 0, 0, 0);
          else
            acc[mf][nf] = __builtin_amdgcn_mfma_f32_16x16x16f16(af[mf], bf[nf], acc[mf][nf], 0, 0, 0);
        }
    }
  };

  GLOAD(0);
  DSW(0);
  LBAR();
#pragma unroll 1
  for (int k = 0; k < 32; ++k) {
    if (k + 1 < 32) GLOAD((k + 1) * 32);  // issued a full phase before consumption
    COMPUTE(k & 1);
    if (k + 1 < 32) {
      DSW((k + 1) & 1);
      LBAR();
    }
  }

#pragma unroll
  for (int mf = 0; mf < 4; ++mf) {
#pragma unroll
    for (int nf = 0; nf < 4; ++nf) {
#pragma unroll
      for (int i = 0; i < 4; ++i) {
        if (MODE == 2) {
          const int srow = bm + wm * 64 + mf * 16 + lr;
          const int dcol = bn + wn * 64 + nf * 16 + 4 * lg + i;
          const float v = acc[mf][nf][i] + bias[dcol];
          const int b = srow >> 11, s = srow & 2047;
          const int h = dcol >> 6, d = dcol & 63;
          ((f16*)outp)[((size_t)(b * N_HEADS + h) * D_K + d) * S_LEN + s] = (f16)v;
        } else {
          const int mrow = bm + wm * 64 + mf * 16 + 4 * lg + i;
          const int ncol = bn + wn * 64 + nf * 16 + lr;
          const float v = acc[mf][nf][i] + bias[ncol];
          const int b = mrow >> 11, s = mrow & 2047;
          const int h = ncol >> 6, d = ncol & 63;
          if (MODE == 0) {
            ((f16*)outp)[((size_t)(b * N_HEADS + h) * S_LEN + s) * D_K + d] = (f16)(v * 0.125f);
          } else if (MODE == 1) {
            ((f16*)outp)[((size_t)(b * N_HEADS + h) * S_LEN + s) * D_K + d] = (f16)v;
          } else {
            ((float*)outp)[(size_t)mrow * D_MODEL + ncol] = v;
          }
        }
      }
    }
  }
}

// ---------------- staged single-pass fused attention (QBLK=64, raw-barrier pipeline) ----------------
// T3/T4: lgkm-only barrier; K/V prefetched 1 phase ahead (L2-resident, ~250cy covered);
// rel (HBM first-touch ~900cy) prefetched 2 phases ahead via two static register sets.
// LDS 52KB -> 3 blocks/CU. NT P' stores.
__global__ __launch_bounds__(256, 3) void attn_staged(const f16* __restrict__ qg, const f16* __restrict__ kg,
                                                      const f16* __restrict__ vTg, const f16* __restrict__ rel16,
                                                      const int* __restrict__ mask, f16* __restrict__ Pbuf,
                                                      float* __restrict__ invb, f16* __restrict__ ctx) {
  const int b = blockIdx.x & 3, qt = blockIdx.x >> 2;
  const int h = blockIdx.y;
  const int t = threadIdx.x, w = t >> 6, lane = t & 63;
  const int lr = lane & 15, lg = lane >> 4;
  const int lr7 = lr & 7;
  const int Ld8 = lane >> 3, Lm8 = lane & 7;

  __shared__ f16 Kc[2][64 * 64];
  __shared__ f16 Vc[2][64 * 64];
  __shared__ f16 Rc[2][64 * 64];
  __shared__ f16 maskh[S_LEN];

  for (int i = t; i < S_LEN; i += 256) maskh[i] = mask[b * S_LEN + i] ? (f16)EXP_NEG8 : (f16)0.f;

  const size_t bh = (size_t)(b * N_HEADS + h);
  const f16* qbh = qg + bh * S_LEN * D_K;
  const f16* kbh = kg + bh * S_LEN * D_K;
  const f16* vbh = vTg + bh * (size_t)D_K * S_LEN;
  const f16* relh = rel16 + (size_t)h * S_LEN * S_LEN;

  const int r0 = qt * 64 + w * 16;
  const int myq = r0 + lr;
  f16* Pq = Pbuf + bh * (size_t)S_LEN * S_LEN + (size_t)myq * S_LEN;

  // staging rows (tile-local); row&7 == Ld8 for both
  const int row0 = w * 16 + Ld8;
  const int row1 = row0 + 8;
  const f16* gK0 = kbh + (size_t)row0 * D_K + Lm8 * 8;
  const f16* gK1 = kbh + (size_t)row1 * D_K + Lm8 * 8;
  const f16* gV0 = vbh + (size_t)row0 * S_LEN + Lm8 * 8;
  const f16* gV1 = vbh + (size_t)row1 * S_LEN + Lm8 * 8;
  const f16* gR0 = relh + (size_t)(qt * 64 + row0) * S_LEN + Lm8 * 8;
  const f16* gR1 = relh + (size_t)(qt * 64 + row1) * S_LEN + Lm8 * 8;
  // swizzled LDS dests (f16 idx)
  const int dK0 = row0 * 64 + ((Lm8 ^ Ld8) << 3);
  const int dK1 = row1 * 64 + ((Lm8 ^ Ld8) << 3);
  const int dVR0 = row0 * 64 + ((((Lm8 << 1) ^ (Ld8 << 1)) & 15) << 2);
  const int dVR1 = row1 * 64 + ((((Lm8 << 1) ^ (Ld8 << 1)) & 15) << 2);

  // Q fragments: qf8[p] covers dk {32p + 8lg .. +7}
  f16x8 qf8[2];
#pragma unroll
  for (int p = 0; p < 2; ++p)
    qf8[p] = *reinterpret_cast<const f16x8*>(&qbh[(size_t)myq * D_K + 32 * p + 8 * lg]);

  float sum = 0.f;
  f32x4 pv[4] = {};

  // K/V staged 1 chunk ahead; rel staged 2 chunks ahead (two static sets, rule #20)
  int4 sK0, sK1, sV0, sV1;
  int4 rgA0, rgA1, rgB0, rgB1;
  auto GKV = [&](int c0) {
    sK0 = *reinterpret_cast<const int4*>(gK0 + (size_t)c0 * D_K);
    sK1 = *reinterpret_cast<const int4*>(gK1 + (size_t)c0 * D_K);
    sV0 = *reinterpret_cast<const int4*>(gV0 + c0);
    sV1 = *reinterpret_cast<const int4*>(gV1 + c0);
  };
  auto LRELA = [&](int c0) {
    rgA0 = *reinterpret_cast<const int4*>(gR0 + c0);
    rgA1 = *reinterpret_cast<const int4*>(gR1 + c0);
  };
  auto LRELB = [&](int c0) {
    rgB0 = *reinterpret_cast<const int4*>(gR0 + c0);
    rgB1 = *reinterpret_cast<const int4*>(gR1 + c0);
  };
  auto DSW = [&](int bb, const int4& r0v, const int4& r1v) {
    *reinterpret_cast<int4*>(&Kc[bb][dK0]) = sK0;
    *reinterpret_cast<int4*>(&Kc[bb][dK1]) = sK1;
    *reinterpret_cast<int4*>(&Vc[bb][dVR0]) = sV0;
    *reinterpret_cast<int4*>(&Vc[bb][dVR1]) = sV1;
    *reinterpret_cast<int4*>(&Rc[bb][dVR0]) = r0v;
    *reinterpret_cast<int4*>(&Rc[bb][dVR1]) = r1v;
  };

  auto CH = [&](int bb, int c0) {
    f32x4 sc[4] = {};
#pragma unroll
    for (int p = 0; p < 2; ++p) {
      const f16x4 qlo = __builtin_shufflevector(qf8[p], qf8[p], 0, 1, 2, 3);
      const f16x4 qhi = __builtin_shufflevector(qf8[p], qf8[p], 4, 5, 6, 7);
#pragma unroll
      for (int j = 0; j < 4; ++j) {
        const f16x8 kv = *reinterpret_cast<const f16x8*>(
            &Kc[bb][(16 * j + lr) * 64 + (((4 * p + lg) ^ lr7) << 3)]);
        sc[j] = __builtin_amdgcn_mfma_f32_16x16x16f16(
            __builtin_shufflevector(kv, kv, 0, 1, 2, 3), qlo, sc[j], 0, 0, 0);
        sc[j] = __builtin_amdgcn_mfma_f32_16x16x16f16(
            __builtin_shufflevector(kv, kv, 4, 5, 6, 7), qhi, sc[j], 0, 0, 0);
      }
    }
#pragma unroll
    for (int j = 0; j < 4; ++j) {
      const int sgp = ((4 * j + lg) ^ (lr7 << 1)) & 15;
      const f16x4 rl = *reinterpret_cast<const f16x4*>(&Rc[bb][(w * 16 + lr) * 64 + (sgp << 2)]);
      const int col = c0 + 16 * j + 4 * lg;
      const f16x4 mh = *reinterpret_cast<const f16x4*>(&maskh[col]);  // broadcast, premult exp(-8)
      const float a0 = __expf(sc[j][0] + (float)rl[0]) * (float)mh[0];
      const float a1 = __expf(sc[j][1] + (float)rl[1]) * (float)mh[1];
      const float a2 = __expf(sc[j][2] + (float)rl[2]) * (float)mh[2];
      const float a3 = __expf(sc[j][3] + (float)rl[3]) * (float)mh[3];
      sum += a0 + a1 + a2 + a3;
      f16x4 pf;
      pf.x = (f16)a0; pf.y = (f16)a1; pf.z = (f16)a2; pf.w = (f16)a3;
      union { f16x4 h; double d; } up;
      up.h = pf;
      __builtin_nontemporal_store(up.d, reinterpret_cast<double*>(&Pq[col]));
#pragma unroll
      for (int nf = 0; nf < 4; ++nf) {
        const f16x4 vf = *reinterpret_cast<const f16x4*>(&Vc[bb][(nf * 16 + lr) * 64 + (sgp << 2)]);
        pv[nf] = __builtin_amdgcn_mfma_f32_16x16x16f16(pf, vf, pv[nf], 0, 0, 0);
      }
    }
  };

  // prologue: chunk0 -> LDS0 (rel via set A); rel(1) preloaded into set B.
  LRELA(0);
  GKV(0);
  DSW(0, rgA0, rgA1);
  LRELB(64);
  LBAR();

  // even phase c: rel(c+2)->A, KV(c+1); CH(c); DSW(c+1, relB); bar
  // odd  phase c: rel(c+2)->B, KV(c+1); CH(c); DSW(c+1, relA); bar
#pragma unroll 1
  for (int cc = 0; cc < 16; ++cc) {
    const int c = 2 * cc;
    if (c + 2 < 32) LRELA((c + 2) * 64);
    GKV((c + 1) * 64);
    CH(0, c * 64);
    DSW(1, rgB0, rgB1);
    LBAR();
    if (c + 3 < 32) LRELB((c + 3) * 64);
    if (c + 2 < 32) GKV((c + 2) * 64);
    CH(1, (c + 1) * 64);
    if (c + 2 < 32) {
      DSW(0, rgA0, rgA1);
      LBAR();
    }
  }

  sum += __shfl_xor(sum, 16, 64);
  sum += __shfl_xor(sum, 32, 64);
  const float inv = 1.f / sum;  // lane holds inv for row myq

  float ivr[4];
#pragma unroll
  for (int i = 0; i < 4; ++i) ivr[i] = __shfl(inv, 4 * lg + i, 64);
#pragma unroll
  for (int nf = 0; nf < 4; ++nf)
#pragma unroll
    for (int i = 0; i < 4; ++i)
      ctx[(size_t)(b * S_LEN + r0 + 4 * lg + i) * D_MODEL + h * D_K + nf * 16 + lr] =
          (f16)(pv[nf][i] * ivr[i]);

  if (lane < 16) invb[bh * S_LEN + r0 + lr] = inv;
}

// ---------------- fallback: single-pass, no staging, rel f32, attn written directly ----------------
__global__ __launch_bounds__(256) void attn_single(const f16* __restrict__ qg, const f16* __restrict__ kg,
                                                   const f16* __restrict__ vTg, const float* __restrict__ relp,
                                                   const int* __restrict__ mask, float* __restrict__ attn_out,
                                                   f16* __restrict__ ctx) {
  const int b = blockIdx.x & 3, qt = blockIdx.x >> 2;
  const int h = blockIdx.y;
  const int t = threadIdx.x, w = t >> 6, lane = t & 63;
  const int lr = lane & 15, lg = lane >> 4;
  __shared__ float mask_f[S_LEN];

  for (int i = t; i < S_LEN; i += 256) mask_f[i] = mask[b * S_LEN + i] ? EXP_NEG8 : 0.f;
  __syncthreads();

  const size_t bh = (size_t)(b * N_HEADS + h);
  const f16* qbh = qg + bh * S_LEN * D_K;
  const f16* kbh = kg + bh * S_LEN * D_K;
  const f16* vbh = vTg + bh * (size_t)D_K * S_LEN;

  const int r0 = qt * 64 + w * 16;
  const int myq = r0 + lr;

  const float* relq32 = relp + (size_t)h * S_LEN * S_LEN + (size_t)myq * S_LEN;
  float* attnq = attn_out + bh * (size_t)S_LEN * S_LEN + (size_t)myq * S_LEN;

  f16x8 qf8[2];
#pragma unroll
  for (int p = 0; p < 2; ++p)
    qf8[p] = *reinterpret_cast<const f16x8*>(&qbh[(size_t)myq * D_K + 32 * p + 8 * lg]);

  float sum = 0.f;
  f32x4 pv[4] = {};

  auto CH = [&](int c0) {
    f32x4 sc[4] = {};
#pragma unroll
    for (int p = 0; p < 2; ++p) {
      const f16x4 qlo = __builtin_shufflevector(qf8[p], qf8[p], 0, 1, 2, 3);
      const f16x4 qhi = __builtin_shufflevector(qf8[p], qf8[p], 4, 5, 6, 7);
#pragma unroll
      for (int j = 0; j < 4; ++j) {
        const f16x8 kv = *reinterpret_cast<const f16x8*>(
            &kbh[(size_t)(c0 + 16 * j + lr) * D_K + 32 * p + 8 * lg]);
        sc[j] = __builtin_amdgcn_mfma_f32_16x16x16f16(
            __builtin_shufflevector(kv, kv, 0, 1, 2, 3), qlo, sc[j], 0, 0, 0);
        sc[j] = __builtin_amdgcn_mfma_f32_16x16x16f16(
            __builtin_shufflevector(kv, kv, 4, 5, 6, 7), qhi, sc[j], 0, 0, 0);
      }
    }
#pragma unroll
    for (int j = 0; j < 4; ++j) {
      const int col = c0 + 16 * j + 4 * lg;
      const float4 rl = *reinterpret_cast<const float4*>(&relq32[col]);
      const float4 mk = *reinterpret_cast<const float4*>(&mask_f[col]);
      const float a0 = __expf(sc[j][0] + rl.x) * mk.x;
      const float a1 = __expf(sc[j][1] + rl.y) * mk.y;
      const float a2 = __expf(sc[j][2] + rl.z) * mk.z;
      const float a3 = __expf(sc[j][3] + rl.w) * mk.w;
      sum += a0 + a1 + a2 + a3;
      f16x4 pf;
      pf.x = (f16)a0; pf.y = (f16)a1; pf.z = (f16)a2; pf.w = (f16)a3;
      *reinterpret_cast<float4*>(&attnq[col]) = make_float4(a0, a1, a2, a3);
#pragma unroll
      for (int nf = 0; nf < 4; ++nf) {
        const f16x4 vf = *reinterpret_cast<const f16x4*>(&vbh[(size_t)(nf * 16 + lr) * S_LEN + col]);
        pv[nf] = __builtin_amdgcn_mfma_f32_16x16x16f16(pf, vf, pv[nf], 0, 0, 0);
      }
    }
  };

#pragma unroll 1
  for (int c0 = 0; c0 < S_LEN; c0 += 64) CH(c0);

  sum += __shfl_xor(sum, 16, 64);
  sum += __shfl_xor(sum, 32, 64);
  const float inv = 1.f / sum;

  float ivr[4];
#pragma unroll
  for (int i = 0; i < 4; ++i) ivr[i] = __shfl(inv, 4 * lg + i, 64);
#pragma unroll
  for (int nf = 0; nf < 4; ++nf)
#pragma unroll
    for (int i = 0; i < 4; ++i)
      ctx[(size_t)(b * S_LEN + r0 + 4 * lg + i) * D_MODEL + h * D_K + nf * 16 + lr] =
          (f16)(pv[nf][i] * ivr[i]);

  // in-place rescale of this wave's 16 rows (f32 RMW)
  float4* aw4 = reinterpret_cast<float4*>(attn_out + bh * (size_t)S_LEN * S_LEN + (size_t)r0 * S_LEN);
#pragma unroll 1
  for (int it = 0; it < 128; it += 4) {
#pragma unroll
    for (int u = 0; u < 4; ++u) {
      const float iv = __shfl(inv, (it + u) >> 3, 64);
      float4 v = aw4[(it + u) * 64 + lane];
      v.x *= iv; v.y *= iv; v.z *= iv; v.w *= iv;
      aw4[(it + u) * 64 + lane] = v;
    }
  }
}

// ---------------- normalize: attn = P'(f16) * inv[row], pure streaming ----------------
__global__ __launch_bounds__(256) void norm_attn(const f16* __restrict__ P, const float* __restrict__ invb,
                                                 float* __restrict__ attn) {
  const size_t total = (size_t)BATCH * N_HEADS * S_LEN * (S_LEN / 8);  // groups of 8
  size_t i = (size_t)blockIdx.x * 256 + threadIdx.x;
  const size_t stride = (size_t)gridDim.x * 256;
  for (; i < total; i += stride) {
    const f16x8 p = reinterpret_cast<const f16x8*>(P)[i];
    const float iv = invb[i >> 8];
    float4 o0 = make_float4((float)p[0] * iv, (float)p[1] * iv, (float)p[2] * iv, (float)p[3] * iv);
    float4 o1 = make_float4((float)p[4] * iv, (float)p[5] * iv, (float)p[6] * iv, (float)p[7] * iv);
    reinterpret_cast<float4*>(attn)[2 * i] = o0;
    reinterpret_cast<float4*>(attn)[2 * i + 1] = o1;
  }
}

extern "C" void kernel_launch(void* const* d_in, const int* in_sizes, int n_in,
                              void* d_out, int out_size, void* d_ws, size_t ws_size,
                              hipStream_t stream) {
  const float* Q    = (const float*)d_in[0];
  const float* K    = (const float*)d_in[1];
  const float* V    = (const float*)d_in[2];
  const int*   mask = (const int*)d_in[3];
  const float* rel  = (const float*)d_in[4];
  const float* Wq   = (const float*)d_in[5];
  const float* bq   = (const float*)d_in[6];
  const float* Wk   = (const float*)d_in[7];
  const float* bk   = (const float*)d_in[8];
  const float* Wv   = (const float*)d_in[9];
  const float* bv   = (const float*)d_in[10];
  const float* Wo   = (const float*)d_in[11];
  const float* bo   = (const float*)d_in[12];

  char* wsb = (char*)d_ws;
  const size_t XSZ = (size_t)BATCH * S_LEN * D_MODEL * sizeof(f16);  // 16.78 MB
  const size_t WSZ = (size_t)D_MODEL * D_MODEL * sizeof(f16);        // 2 MB
  f16* WqT = (f16*)(wsb);
  f16* WkT = (f16*)(wsb + WSZ);
  f16* WvT = (f16*)(wsb + 2 * WSZ);
  f16* WoT = (f16*)(wsb + 3 * WSZ);
  f16* qb  = (f16*)(wsb + 4 * WSZ);
  f16* kb  = (f16*)(wsb + 4 * WSZ + XSZ);
  f16* vTb = (f16*)(wsb + 4 * WSZ + 2 * XSZ);
  f16* ctx = (f16*)(wsb + 4 * WSZ + 3 * XSZ);

  const size_t BASE  = 4 * WSZ + 4 * XSZ;                                        // 75.5 MB
  const size_t RELSZ = (size_t)N_HEADS * S_LEN * S_LEN * sizeof(f16);            // 134,217,728
  const size_t PSZ   = (size_t)BATCH * N_HEADS * S_LEN * S_LEN * sizeof(f16);    // 536,870,912
  const size_t INVSZ = (size_t)BATCH * N_HEADS * S_LEN * sizeof(float);          // 524,288
  f16*   rel16 = (f16*)(wsb + BASE);
  f16*   Pbuf  = (f16*)(wsb + BASE + RELSZ);
  float* invb  = (float*)(wsb + BASE + RELSZ + PSZ);
  const bool pf16 = ws_size >= BASE + RELSZ + PSZ + INVSZ;

  float* out0 = (float*)d_out;
  float* attn = out0 + (size_t)BATCH * S_LEN * D_MODEL;

  wtrans4<<<dim3(32, 32, 4), dim3(32, 8), 0, stream>>>(Wq, Wk, Wv, Wo, WqT, WkT, WvT, WoT);
  if (pf16) {
    const int nr4 = N_HEADS * S_LEN * S_LEN / 4;  // 16,777,216
    cvt_f32_f16<<<dim3(nr4 / 256), 256, 0, stream>>>(rel, rel16, nr4);
  }

  gemm16<0, true><<<dim3(8, 64), 256, 0, stream>>>(Q, WqT, bq, qb);
  gemm16<1, true><<<dim3(8, 64), 256, 0, stream>>>(K, WkT, bk, kb);
  gemm16<2, true><<<dim3(8, 64), 256, 0, stream>>>(V, WvT, bv, vTb);

  if (pf16) {
    attn_staged<<<dim3(BATCH * (S_LEN / 64), N_HEADS), 256, 0, stream>>>(qb, kb, vTb, rel16, mask,
                                                                         Pbuf, invb, ctx);
    norm_attn<<<dim3(16384), 256, 0, stream>>>(Pbuf, invb, attn);
  } else {
    attn_single<<<dim3(BATCH * (S_LEN / 64), N_HEADS), 256, 0, stream>>>(qb, kb, vTb, rel, mask,
                                                                         attn, ctx);
  }

  gemm16<3, false><<<dim3(8, 64), 256, 0, stream>>>(ctx, WoT, bo, (void*)out0);
}

// Round 12
// 703.750 us; speedup vs baseline: 1.3139x; 1.3139x over previous
//
#include <hip/hip_runtime.h>
#include <hip/hip_fp16.h>

typedef _Float16 f16;
typedef __attribute__((ext_vector_type(4))) _Float16 f16x4;
typedef __attribute__((ext_vector_type(8))) _Float16 f16x8;
typedef __attribute__((ext_vector_type(4))) float f32x4;

#define S_LEN 2048
#define D_MODEL 1024
#define N_HEADS 16
#define D_K 64
#define BATCH 4

// exp(-8): folded into mask so unnormalized e = exp(score+rel-8)*mask stays small.
// Common to every unmasked column -> cancels exactly in e/sum (f16 quantization included).
#define EXP_NEG8 3.35462627903e-4f

// lgkmcnt-only barrier: does NOT drain vmcnt, so staged global loads stay in flight across it.
#define LBAR() do { asm volatile("s_waitcnt lgkmcnt(0)" ::: "memory"); \
                    __builtin_amdgcn_s_barrier(); } while (0)

// ---------------- fp32 -> fp16 convert (vectorized) ----------------
__global__ void cvt_f32_f16(const float* __restrict__ src, f16* __restrict__ dst, int n4) {
  int i = blockIdx.x * blockDim.x + threadIdx.x;
  if (i < n4) {
    const float4 v = reinterpret_cast<const float4*>(src)[i];
    f16x4 h;
    h.x = (f16)v.x; h.y = (f16)v.y; h.z = (f16)v.z; h.w = (f16)v.w;
    reinterpret_cast<f16x4*>(dst)[i] = h;
  }
}

// batched Q/K/V convert (one launch)
__global__ void cvt3(const float* __restrict__ s0, const float* __restrict__ s1,
                     const float* __restrict__ s2, f16* __restrict__ d0, f16* __restrict__ d1,
                     f16* __restrict__ d2, int n4) {
  const float* s = blockIdx.y == 0 ? s0 : (blockIdx.y == 1 ? s1 : s2);
  f16* d = blockIdx.y == 0 ? d0 : (blockIdx.y == 1 ? d1 : d2);
  int i = blockIdx.x * blockDim.x + threadIdx.x;
  if (i < n4) {
    const float4 v = reinterpret_cast<const float4*>(s)[i];
    f16x4 h;
    h.x = (f16)v.x; h.y = (f16)v.y; h.z = (f16)v.z; h.w = (f16)v.w;
    reinterpret_cast<f16x4*>(d)[i] = h;
  }
}

// ---------------- weight transpose + convert (batched over 4 weights) ----------------
__global__ void wtrans4(const float* __restrict__ W0, const float* __restrict__ W1,
                        const float* __restrict__ W2, const float* __restrict__ W3,
                        f16* __restrict__ T0, f16* __restrict__ T1, f16* __restrict__ T2,
                        f16* __restrict__ T3) {
  const float* W = blockIdx.z == 0 ? W0 : (blockIdx.z == 1 ? W1 : (blockIdx.z == 2 ? W2 : W3));
  f16* WT = blockIdx.z == 0 ? T0 : (blockIdx.z == 1 ? T1 : (blockIdx.z == 2 ? T2 : T3));
  __shared__ float tile[32][33];
  const int n0 = blockIdx.x * 32, k0 = blockIdx.y * 32;
  const int tx = threadIdx.x, ty = threadIdx.y;  // block (32,8)
#pragma unroll
  for (int i = 0; i < 4; ++i)
    tile[ty + i * 8][tx] = W[(size_t)(k0 + ty + i * 8) * D_MODEL + n0 + tx];
  __syncthreads();
#pragma unroll
  for (int i = 0; i < 4; ++i)
    WT[(size_t)(n0 + ty + i * 8) * D_MODEL + k0 + tx] = (f16)tile[tx][ty + i * 8];
}

// ---------------- GEMM: C[8192][1024] = A(f16) @ W + bias, W given as WT[n][k] ----------------
// Raw-barrier pipelined (r9-proven): one lgkm-only barrier per K-step; staged global loads
// issued a full compute-phase before their ds_write. MODE 2 swaps MFMA operands so the
// D-tile is transposed in-register -> coalesced V^T stores.
template <int MODE>
__global__ __launch_bounds__(256, 3) void gemm16(const f16* __restrict__ A, const f16* __restrict__ BT,
                                                 const float* __restrict__ bias, void* __restrict__ outp) {
  __shared__ f16 As[2][128 * 40];
  __shared__ f16 Bs[2][128 * 40];
  const int t = threadIdx.x;
  const int lane = t & 63, wid = t >> 6;
  const int wm = wid >> 1, wn = wid & 1;
  const int lr = lane & 15, lg = lane >> 4;
  const int bm = blockIdx.y * 128, bn = blockIdx.x * 128;

  f32x4 acc[4][4] = {};

  const int r0s = t >> 2, g0 = (t & 3) * 8;
  const f16* gA0 = &A[(size_t)(bm + r0s) * 1024 + g0];
  const f16* gA1 = gA0 + (size_t)64 * 1024;
  const f16* gB0 = &BT[(size_t)(bn + r0s) * 1024 + g0];
  const f16* gB1 = gB0 + (size_t)64 * 1024;
  const int dst0 = r0s * 40 + g0, dst1 = (r0s + 64) * 40 + g0;

  int4 sA0, sA1, sB0, sB1;
  auto GLOAD = [&](int k0) {
    sA0 = *reinterpret_cast<const int4*>(gA0 + k0);
    sA1 = *reinterpret_cast<const int4*>(gA1 + k0);
    sB0 = *reinterpret_cast<const int4*>(gB0 + k0);
    sB1 = *reinterpret_cast<const int4*>(gB1 + k0);
  };
  auto DSW = [&](int bb) {
    *reinterpret_cast<int4*>(&As[bb][dst0]) = sA0;
    *reinterpret_cast<int4*>(&As[bb][dst1]) = sA1;
    *reinterpret_cast<int4*>(&Bs[bb][dst0]) = sB0;
    *reinterpret_cast<int4*>(&Bs[bb][dst1]) = sB1;
  };
  auto COMPUTE = [&](int bb) {
#pragma unroll
    for (int kk = 0; kk < 2; ++kk) {
      f16x4 af[4], bf[4];
#pragma unroll
      for (int mf = 0; mf < 4; ++mf)
        af[mf] = *reinterpret_cast<const f16x4*>(&As[bb][(wm * 64 + mf * 16 + lr) * 40 + kk * 16 + 4 * lg]);
#pragma unroll
      for (int nf = 0; nf < 4; ++nf)
        bf[nf] = *reinterpret_cast<const f16x4*>(&Bs[bb][(wn * 64 + nf * 16 + lr) * 40 + kk * 16 + 4 * lg]);
#pragma unroll
      for (int mf = 0; mf < 4; ++mf)
#pragma unroll
        for (int nf = 0; nf < 4; ++nf) {
          if (MODE == 2)
            acc[mf][nf] = __builtin_amdgcn_mfma_f32_16x16x16f16(bf[nf], af[mf], acc[mf][nf], 0, 0, 0);
          else
            acc[mf][nf] = __builtin_amdgcn_mfma_f32_16x16x16f16(af[mf], bf[nf], acc[mf][nf], 0, 0, 0);
        }
    }
  };

  GLOAD(0);
  DSW(0);
  LBAR();
#pragma unroll 1
  for (int k = 0; k < 32; ++k) {
    if (k + 1 < 32) GLOAD((k + 1) * 32);
    COMPUTE(k & 1);
    if (k + 1 < 32) {
      DSW((k + 1) & 1);
      LBAR();
    }
  }

#pragma unroll
  for (int mf = 0; mf < 4; ++mf) {
#pragma unroll
    for (int nf = 0; nf < 4; ++nf) {
#pragma unroll
      for (int i = 0; i < 4; ++i) {
        if (MODE == 2) {
          const int srow = bm + wm * 64 + mf * 16 + lr;
          const int dcol = bn + wn * 64 + nf * 16 + 4 * lg + i;
          const float v = acc[mf][nf][i] + bias[dcol];
          const int b = srow >> 11, s = srow & 2047;
          const int h = dcol >> 6, d = dcol & 63;
          ((f16*)outp)[((size_t)(b * N_HEADS + h) * D_K + d) * S_LEN + s] = (f16)v;
        } else {
          const int mrow = bm + wm * 64 + mf * 16 + 4 * lg + i;
          const int ncol = bn + wn * 64 + nf * 16 + lr;
          const float v = acc[mf][nf][i] + bias[ncol];
          const int b = mrow >> 11, s = mrow & 2047;
          const int h = ncol >> 6, d = ncol & 63;
          if (MODE == 0) {
            ((f16*)outp)[((size_t)(b * N_HEADS + h) * S_LEN + s) * D_K + d] = (f16)(v * 0.125f);
          } else if (MODE == 1) {
            ((f16*)outp)[((size_t)(b * N_HEADS + h) * S_LEN + s) * D_K + d] = (f16)v;
          } else {
            ((float*)outp)[(size_t)mrow * D_MODEL + ncol] = v;
          }
        }
      }
    }
  }
}

// ---------------- two-sweep fused attention: sums, then normalized direct write + PV ----------
// Sweep 1: pipelined QK^T + rel + exp -> per-row sums (no stores, no V).
// Sweep 2: recompute scores (inputs L2-hot), normalize IN-LANE (lane owns q-row = lr),
//          NT-write f32 attn directly, PV with normalized P -> ctx (no inv shuffles anywhere).
// Eliminates the P' buffer (1.07 GB round-trip) and the norm_attn kernel.
__global__ __launch_bounds__(256, 3) void attn_fused2(const f16* __restrict__ qg, const f16* __restrict__ kg,
                                                      const f16* __restrict__ vTg, const f16* __restrict__ rel16,
                                                      const int* __restrict__ mask, float* __restrict__ attn_out,
                                                      f16* __restrict__ ctx) {
  const int b = blockIdx.x & 3, qt = blockIdx.x >> 2;
  const int h = blockIdx.y;
  const int t = threadIdx.x, w = t >> 6, lane = t & 63;
  const int lr = lane & 15, lg = lane >> 4;
  const int lr7 = lr & 7;
  const int Ld8 = lane >> 3, Lm8 = lane & 7;

  __shared__ f16 Kc[2][64 * 64];
  __shared__ f16 Vc[2][64 * 64];
  __shared__ f16 Rc[2][64 * 64];
  __shared__ f16 maskh[S_LEN];

  for (int i = t; i < S_LEN; i += 256) maskh[i] = mask[b * S_LEN + i] ? (f16)EXP_NEG8 : (f16)0.f;

  const size_t bh = (size_t)(b * N_HEADS + h);
  const f16* qbh = qg + bh * S_LEN * D_K;
  const f16* kbh = kg + bh * S_LEN * D_K;
  const f16* vbh = vTg + bh * (size_t)D_K * S_LEN;
  const f16* relh = rel16 + (size_t)h * S_LEN * S_LEN;

  const int r0 = qt * 64 + w * 16;
  const int myq = r0 + lr;
  float* attnq = attn_out + bh * (size_t)S_LEN * S_LEN + (size_t)myq * S_LEN;

  // staging rows (tile-local); row&7 == Ld8 for both
  const int row0 = w * 16 + Ld8;
  const int row1 = row0 + 8;
  const f16* gK0 = kbh + (size_t)row0 * D_K + Lm8 * 8;
  const f16* gK1 = kbh + (size_t)row1 * D_K + Lm8 * 8;
  const f16* gV0 = vbh + (size_t)row0 * S_LEN + Lm8 * 8;
  const f16* gV1 = vbh + (size_t)row1 * S_LEN + Lm8 * 8;
  const f16* gR0 = relh + (size_t)(qt * 64 + row0) * S_LEN + Lm8 * 8;
  const f16* gR1 = relh + (size_t)(qt * 64 + row1) * S_LEN + Lm8 * 8;
  // swizzled LDS dests (f16 idx)
  const int dK0 = row0 * 64 + ((Lm8 ^ Ld8) << 3);
  const int dK1 = row1 * 64 + ((Lm8 ^ Ld8) << 3);
  const int dVR0 = row0 * 64 + ((((Lm8 << 1) ^ (Ld8 << 1)) & 15) << 2);
  const int dVR1 = row1 * 64 + ((((Lm8 << 1) ^ (Ld8 << 1)) & 15) << 2);

  // Q fragments: qf8[p] covers dk {32p + 8lg .. +7}
  f16x8 qf8[2];
#pragma unroll
  for (int p = 0; p < 2; ++p)
    qf8[p] = *reinterpret_cast<const f16x8*>(&qbh[(size_t)myq * D_K + 32 * p + 8 * lg]);

  int4 sK0, sK1, sV0, sV1, sR0, sR1;
  auto GK = [&](int c0) {
    sK0 = *reinterpret_cast<const int4*>(gK0 + (size_t)c0 * D_K);
    sK1 = *reinterpret_cast<const int4*>(gK1 + (size_t)c0 * D_K);
  };
  auto GV = [&](int c0) {
    sV0 = *reinterpret_cast<const int4*>(gV0 + c0);
    sV1 = *reinterpret_cast<const int4*>(gV1 + c0);
  };
  auto GR = [&](int c0) {
    sR0 = *reinterpret_cast<const int4*>(gR0 + c0);
    sR1 = *reinterpret_cast<const int4*>(gR1 + c0);
  };
  auto DSW1 = [&](int bb) {  // K + rel only (sweep 1)
    *reinterpret_cast<int4*>(&Kc[bb][dK0]) = sK0;
    *reinterpret_cast<int4*>(&Kc[bb][dK1]) = sK1;
    *reinterpret_cast<int4*>(&Rc[bb][dVR0]) = sR0;
    *reinterpret_cast<int4*>(&Rc[bb][dVR1]) = sR1;
  };
  auto DSW2 = [&](int bb) {  // K + V + rel (sweep 2)
    *reinterpret_cast<int4*>(&Kc[bb][dK0]) = sK0;
    *reinterpret_cast<int4*>(&Kc[bb][dK1]) = sK1;
    *reinterpret_cast<int4*>(&Vc[bb][dVR0]) = sV0;
    *reinterpret_cast<int4*>(&Vc[bb][dVR1]) = sV1;
    *reinterpret_cast<int4*>(&Rc[bb][dVR0]) = sR0;
    *reinterpret_cast<int4*>(&Rc[bb][dVR1]) = sR1;
  };

  auto SCORES = [&](int bb, f32x4 (&sc)[4]) {
#pragma unroll
    for (int p = 0; p < 2; ++p) {
      const f16x4 qlo = __builtin_shufflevector(qf8[p], qf8[p], 0, 1, 2, 3);
      const f16x4 qhi = __builtin_shufflevector(qf8[p], qf8[p], 4, 5, 6, 7);
#pragma unroll
      for (int j = 0; j < 4; ++j) {
        const f16x8 kv = *reinterpret_cast<const f16x8*>(
            &Kc[bb][(16 * j + lr) * 64 + (((4 * p + lg) ^ lr7) << 3)]);
        sc[j] = __builtin_amdgcn_mfma_f32_16x16x16f16(
            __builtin_shufflevector(kv, kv, 0, 1, 2, 3), qlo, sc[j], 0, 0, 0);
        sc[j] = __builtin_amdgcn_mfma_f32_16x16x16f16(
            __builtin_shufflevector(kv, kv, 4, 5, 6, 7), qhi, sc[j], 0, 0, 0);
      }
    }
  };

  // ---- sweep 1: row sums ----
  float sum = 0.f;
  GK(0);
  GR(0);
  DSW1(0);
  LBAR();
#pragma unroll 1
  for (int c = 0; c < 32; ++c) {
    if (c + 1 < 32) {
      GK((c + 1) * 64);
      GR((c + 1) * 64);
    }
    const int bb = c & 1;
    f32x4 sc[4] = {};
    SCORES(bb, sc);
#pragma unroll
    for (int j = 0; j < 4; ++j) {
      const int sgp = ((4 * j + lg) ^ (lr7 << 1)) & 15;
      const f16x4 rl = *reinterpret_cast<const f16x4*>(&Rc[bb][(w * 16 + lr) * 64 + (sgp << 2)]);
      const int col = c * 64 + 16 * j + 4 * lg;
      const f16x4 mh = *reinterpret_cast<const f16x4*>(&maskh[col]);
      sum += __expf(sc[j][0] + (float)rl[0]) * (float)mh[0] +
             __expf(sc[j][1] + (float)rl[1]) * (float)mh[1] +
             __expf(sc[j][2] + (float)rl[2]) * (float)mh[2] +
             __expf(sc[j][3] + (float)rl[3]) * (float)mh[3];
    }
    if (c + 1 < 32) {
      DSW1((c + 1) & 1);
      LBAR();
    }
  }
  sum += __shfl_xor(sum, 16, 64);
  sum += __shfl_xor(sum, 32, 64);
  const float inv = 1.f / sum;  // lane-local: this lane's q-row is myq = r0 + lr

  // ---- sweep 2: normalized attn write + PV ----
  f32x4 pv[4] = {};
  GK(0);
  GV(0);
  GR(0);
  DSW2(0);   // writes buf0; any wave still in sweep-1 c=31 only reads buf1 -> safe
  LBAR();
#pragma unroll 1
  for (int c = 0; c < 32; ++c) {
    if (c + 1 < 32) {
      GK((c + 1) * 64);
      GV((c + 1) * 64);
      GR((c + 1) * 64);
    }
    const int bb = c & 1;
    f32x4 sc[4] = {};
    SCORES(bb, sc);
#pragma unroll
    for (int j = 0; j < 4; ++j) {
      const int sgp = ((4 * j + lg) ^ (lr7 << 1)) & 15;
      const f16x4 rl = *reinterpret_cast<const f16x4*>(&Rc[bb][(w * 16 + lr) * 64 + (sgp << 2)]);
      const int col = c * 64 + 16 * j + 4 * lg;
      const f16x4 mh = *reinterpret_cast<const f16x4*>(&maskh[col]);
      const float a0 = __expf(sc[j][0] + (float)rl[0]) * (float)mh[0] * inv;
      const float a1 = __expf(sc[j][1] + (float)rl[1]) * (float)mh[1] * inv;
      const float a2 = __expf(sc[j][2] + (float)rl[2]) * (float)mh[2] * inv;
      const float a3 = __expf(sc[j][3] + (float)rl[3]) * (float)mh[3] * inv;
      f32x4 av = {a0, a1, a2, a3};
      __builtin_nontemporal_store(av, reinterpret_cast<f32x4*>(&attnq[col]));
      f16x4 pf;
      pf.x = (f16)a0; pf.y = (f16)a1; pf.z = (f16)a2; pf.w = (f16)a3;
#pragma unroll
      for (int nf = 0; nf < 4; ++nf) {
        const f16x4 vf = *reinterpret_cast<const f16x4*>(&Vc[bb][(nf * 16 + lr) * 64 + (sgp << 2)]);
        pv[nf] = __builtin_amdgcn_mfma_f32_16x16x16f16(pf, vf, pv[nf], 0, 0, 0);
      }
    }
    if (c + 1 < 32) {
      DSW2((c + 1) & 1);
      LBAR();
    }
  }

  // pv is already normalized (pf carried inv); D-layout rows r0+4lg+i
#pragma unroll
  for (int nf = 0; nf < 4; ++nf)
#pragma unroll
    for (int i = 0; i < 4; ++i)
      ctx[(size_t)(b * S_LEN + r0 + 4 * lg + i) * D_MODEL + h * D_K + nf * 16 + lr] =
          (f16)pv[nf][i];
}

// ---------------- fallback: single-pass, no staging, rel f32, attn written directly ----------------
__global__ __launch_bounds__(256) void attn_single(const f16* __restrict__ qg, const f16* __restrict__ kg,
                                                   const f16* __restrict__ vTg, const float* __restrict__ relp,
                                                   const int* __restrict__ mask, float* __restrict__ attn_out,
                                                   f16* __restrict__ ctx) {
  const int b = blockIdx.x & 3, qt = blockIdx.x >> 2;
  const int h = blockIdx.y;
  const int t = threadIdx.x, w = t >> 6, lane = t & 63;
  const int lr = lane & 15, lg = lane >> 4;
  __shared__ float mask_f[S_LEN];

  for (int i = t; i < S_LEN; i += 256) mask_f[i] = mask[b * S_LEN + i] ? EXP_NEG8 : 0.f;
  __syncthreads();

  const size_t bh = (size_t)(b * N_HEADS + h);
  const f16* qbh = qg + bh * S_LEN * D_K;
  const f16* kbh = kg + bh * S_LEN * D_K;
  const f16* vbh = vTg + bh * (size_t)D_K * S_LEN;

  const int r0 = qt * 64 + w * 16;
  const int myq = r0 + lr;

  const float* relq32 = relp + (size_t)h * S_LEN * S_LEN + (size_t)myq * S_LEN;
  float* attnq = attn_out + bh * (size_t)S_LEN * S_LEN + (size_t)myq * S_LEN;

  f16x8 qf8[2];
#pragma unroll
  for (int p = 0; p < 2; ++p)
    qf8[p] = *reinterpret_cast<const f16x8*>(&qbh[(size_t)myq * D_K + 32 * p + 8 * lg]);

  float sum = 0.f;
  f32x4 pv[4] = {};

  auto CH = [&](int c0) {
    f32x4 sc[4] = {};
#pragma unroll
    for (int p = 0; p < 2; ++p) {
      const f16x4 qlo = __builtin_shufflevector(qf8[p], qf8[p], 0, 1, 2, 3);
      const f16x4 qhi = __builtin_shufflevector(qf8[p], qf8[p], 4, 5, 6, 7);
#pragma unroll
      for (int j = 0; j < 4; ++j) {
        const f16x8 kv = *reinterpret_cast<const f16x8*>(
            &kbh[(size_t)(c0 + 16 * j + lr) * D_K + 32 * p + 8 * lg]);
        sc[j] = __builtin_amdgcn_mfma_f32_16x16x16f16(
            __builtin_shufflevector(kv, kv, 0, 1, 2, 3), qlo, sc[j], 0, 0, 0);
        sc[j] = __builtin_amdgcn_mfma_f32_16x16x16f16(
            __builtin_shufflevector(kv, kv, 4, 5, 6, 7), qhi, sc[j], 0, 0, 0);
      }
    }
#pragma unroll
    for (int j = 0; j < 4; ++j) {
      const int col = c0 + 16 * j + 4 * lg;
      const float4 rl = *reinterpret_cast<const float4*>(&relq32[col]);
      const float4 mk = *reinterpret_cast<const float4*>(&mask_f[col]);
      const float a0 = __expf(sc[j][0] + rl.x) * mk.x;
      const float a1 = __expf(sc[j][1] + rl.y) * mk.y;
      const float a2 = __expf(sc[j][2] + rl.z) * mk.z;
      const float a3 = __expf(sc[j][3] + rl.w) * mk.w;
      sum += a0 + a1 + a2 + a3;
      f16x4 pf;
      pf.x = (f16)a0; pf.y = (f16)a1; pf.z = (f16)a2; pf.w = (f16)a3;
      *reinterpret_cast<float4*>(&attnq[col]) = make_float4(a0, a1, a2, a3);
#pragma unroll
      for (int nf = 0; nf < 4; ++nf) {
        const f16x4 vf = *reinterpret_cast<const f16x4*>(&vbh[(size_t)(nf * 16 + lr) * S_LEN + col]);
        pv[nf] = __builtin_amdgcn_mfma_f32_16x16x16f16(pf, vf, pv[nf], 0, 0, 0);
      }
    }
  };

#pragma unroll 1
  for (int c0 = 0; c0 < S_LEN; c0 += 64) CH(c0);

  sum += __shfl_xor(sum, 16, 64);
  sum += __shfl_xor(sum, 32, 64);
  const float inv = 1.f / sum;

  float ivr[4];
#pragma unroll
  for (int i = 0; i < 4; ++i) ivr[i] = __shfl(inv, 4 * lg + i, 64);
#pragma unroll
  for (int nf = 0; nf < 4; ++nf)
#pragma unroll
    for (int i = 0; i < 4; ++i)
      ctx[(size_t)(b * S_LEN + r0 + 4 * lg + i) * D_MODEL + h * D_K + nf * 16 + lr] =
          (f16)(pv[nf][i] * ivr[i]);

  // in-place rescale of this wave's 16 rows (f32 RMW)
  float4* aw4 = reinterpret_cast<float4*>(attn_out + bh * (size_t)S_LEN * S_LEN + (size_t)r0 * S_LEN);
#pragma unroll 1
  for (int it = 0; it < 128; it += 4) {
#pragma unroll
    for (int u = 0; u < 4; ++u) {
      const float iv = __shfl(inv, (it + u) >> 3, 64);
      float4 v = aw4[(it + u) * 64 + lane];
      v.x *= iv; v.y *= iv; v.z *= iv; v.w *= iv;
      aw4[(it + u) * 64 + lane] = v;
    }
  }
}

extern "C" void kernel_launch(void* const* d_in, const int* in_sizes, int n_in,
                              void* d_out, int out_size, void* d_ws, size_t ws_size,
                              hipStream_t stream) {
  const float* Q    = (const float*)d_in[0];
  const float* K    = (const float*)d_in[1];
  const float* V    = (const float*)d_in[2];
  const int*   mask = (const int*)d_in[3];
  const float* rel  = (const float*)d_in[4];
  const float* Wq   = (const float*)d_in[5];
  const float* bq   = (const float*)d_in[6];
  const float* Wk   = (const float*)d_in[7];
  const float* bk   = (const float*)d_in[8];
  const float* Wv   = (const float*)d_in[9];
  const float* bv   = (const float*)d_in[10];
  const float* Wo   = (const float*)d_in[11];
  const float* bo   = (const float*)d_in[12];

  char* wsb = (char*)d_ws;
  const size_t XSZ = (size_t)BATCH * S_LEN * D_MODEL * sizeof(f16);  // 16.78 MB
  const size_t WSZ = (size_t)D_MODEL * D_MODEL * sizeof(f16);        // 2 MB
  f16* Qh  = (f16*)(wsb);
  f16* Kh  = (f16*)(wsb + XSZ);
  f16* Vh  = (f16*)(wsb + 2 * XSZ);
  f16* WqT = (f16*)(wsb + 3 * XSZ);
  f16* WkT = (f16*)(wsb + 3 * XSZ + WSZ);
  f16* WvT = (f16*)(wsb + 3 * XSZ + 2 * WSZ);
  f16* WoT = (f16*)(wsb + 3 * XSZ + 3 * WSZ);
  f16* qb  = (f16*)(wsb + 3 * XSZ + 4 * WSZ);
  f16* kb  = (f16*)(wsb + 4 * XSZ + 4 * WSZ);
  f16* vTb = (f16*)(wsb + 5 * XSZ + 4 * WSZ);
  f16* ctx = (f16*)(wsb + 6 * XSZ + 4 * WSZ);

  const size_t BASE  = 7 * XSZ + 4 * WSZ;                                 // 125.8 MB
  const size_t RELSZ = (size_t)N_HEADS * S_LEN * S_LEN * sizeof(f16);     // 134.2 MB
  f16* rel16 = (f16*)(wsb + BASE);
  const bool r16 = ws_size >= BASE + RELSZ;

  float* out0 = (float*)d_out;
  float* attn = out0 + (size_t)BATCH * S_LEN * D_MODEL;

  const int n4 = BATCH * S_LEN * D_MODEL / 4;  // 2097152
  cvt3<<<dim3(n4 / 256, 3), 256, 0, stream>>>(Q, K, V, Qh, Kh, Vh, n4);
  wtrans4<<<dim3(32, 32, 4), dim3(32, 8), 0, stream>>>(Wq, Wk, Wv, Wo, WqT, WkT, WvT, WoT);
  if (r16) {
    const int nr4 = N_HEADS * S_LEN * S_LEN / 4;  // 16,777,216
    cvt_f32_f16<<<dim3(nr4 / 256), 256, 0, stream>>>(rel, rel16, nr4);
  }

  gemm16<0><<<dim3(8, 64), 256, 0, stream>>>(Qh, WqT, bq, qb);
  gemm16<1><<<dim3(8, 64), 256, 0, stream>>>(Kh, WkT, bk, kb);
  gemm16<2><<<dim3(8, 64), 256, 0, stream>>>(Vh, WvT, bv, vTb);

  if (r16) {
    attn_fused2<<<dim3(BATCH * (S_LEN / 64), N_HEADS), 256, 0, stream>>>(qb, kb, vTb, rel16, mask,
                                                                         attn, ctx);
  } else {
    attn_single<<<dim3(BATCH * (S_LEN / 64), N_HEADS), 256, 0, stream>>>(qb, kb, vTb, rel, mask,
                                                                         attn, ctx);
  }

  gemm16<3><<<dim3(8, 64), 256, 0, stream>>>(ctx, WoT, bo, (void*)out0);
}

// Round 13
// 694.062 us; speedup vs baseline: 1.3322x; 1.0140x over previous
//
#include <hip/hip_runtime.h>
#include <hip/hip_fp16.h>

typedef _Float16 f16;
typedef __attribute__((ext_vector_type(4))) _Float16 f16x4;
typedef __attribute__((ext_vector_type(8))) _Float16 f16x8;
typedef __attribute__((ext_vector_type(4))) float f32x4;

#define S_LEN 2048
#define D_MODEL 1024
#define N_HEADS 16
#define D_K 64
#define BATCH 4

// exp(-8): folded into mask so unnormalized e = exp(score+rel-8)*mask stays small.
// Common to every unmasked column -> cancels exactly in e/sum (f16 quantization included).
#define EXP_NEG8 3.35462627903e-4f

// lgkmcnt-only barrier: does NOT drain vmcnt, so staged global loads stay in flight across it.
#define LBAR() do { asm volatile("s_waitcnt lgkmcnt(0)" ::: "memory"); \
                    __builtin_amdgcn_s_barrier(); } while (0)

// ---------------- fp32 -> fp16 convert (vectorized) ----------------
__global__ void cvt_f32_f16(const float* __restrict__ src, f16* __restrict__ dst, int n4) {
  int i = blockIdx.x * blockDim.x + threadIdx.x;
  if (i < n4) {
    const float4 v = reinterpret_cast<const float4*>(src)[i];
    f16x4 h;
    h.x = (f16)v.x; h.y = (f16)v.y; h.z = (f16)v.z; h.w = (f16)v.w;
    reinterpret_cast<f16x4*>(dst)[i] = h;
  }
}

// batched Q/K/V convert (one launch)
__global__ void cvt3(const float* __restrict__ s0, const float* __restrict__ s1,
                     const float* __restrict__ s2, f16* __restrict__ d0, f16* __restrict__ d1,
                     f16* __restrict__ d2, int n4) {
  const float* s = blockIdx.y == 0 ? s0 : (blockIdx.y == 1 ? s1 : s2);
  f16* d = blockIdx.y == 0 ? d0 : (blockIdx.y == 1 ? d1 : d2);
  int i = blockIdx.x * blockDim.x + threadIdx.x;
  if (i < n4) {
    const float4 v = reinterpret_cast<const float4*>(s)[i];
    f16x4 h;
    h.x = (f16)v.x; h.y = (f16)v.y; h.z = (f16)v.z; h.w = (f16)v.w;
    reinterpret_cast<f16x4*>(d)[i] = h;
  }
}

// ---------------- weight transpose + convert (batched over 4 weights) ----------------
__global__ void wtrans4(const float* __restrict__ W0, const float* __restrict__ W1,
                        const float* __restrict__ W2, const float* __restrict__ W3,
                        f16* __restrict__ T0, f16* __restrict__ T1, f16* __restrict__ T2,
                        f16* __restrict__ T3) {
  const float* W = blockIdx.z == 0 ? W0 : (blockIdx.z == 1 ? W1 : (blockIdx.z == 2 ? W2 : W3));
  f16* WT = blockIdx.z == 0 ? T0 : (blockIdx.z == 1 ? T1 : (blockIdx.z == 2 ? T2 : T3));
  __shared__ float tile[32][33];
  const int n0 = blockIdx.x * 32, k0 = blockIdx.y * 32;
  const int tx = threadIdx.x, ty = threadIdx.y;  // block (32,8)
#pragma unroll
  for (int i = 0; i < 4; ++i)
    tile[ty + i * 8][tx] = W[(size_t)(k0 + ty + i * 8) * D_MODEL + n0 + tx];
  __syncthreads();
#pragma unroll
  for (int i = 0; i < 4; ++i)
    WT[(size_t)(n0 + ty + i * 8) * D_MODEL + k0 + tx] = (f16)tile[tx][ty + i * 8];
}

// ---------------- merged QKV projection GEMM (grid.z selects Q/K/V) ----------------
// 1536 blocks = 6 blocks/CU (vs 2/CU for a single projection): 3x wave parallelism.
// z==2 (V) uses operand-swapped MFMA -> transposed D-tile -> coalesced V^T stores.
__global__ __launch_bounds__(256, 3) void gemmQKV(const f16* __restrict__ Qh, const f16* __restrict__ Kh,
                                                  const f16* __restrict__ Vh, const f16* __restrict__ WqT,
                                                  const f16* __restrict__ WkT, const f16* __restrict__ WvT,
                                                  const float* __restrict__ bq, const float* __restrict__ bk,
                                                  const float* __restrict__ bv, f16* __restrict__ qb,
                                                  f16* __restrict__ kb, f16* __restrict__ vTb) {
  const int z = blockIdx.z;
  const f16* A = z == 0 ? Qh : (z == 1 ? Kh : Vh);
  const f16* BT = z == 0 ? WqT : (z == 1 ? WkT : WvT);
  const float* bias = z == 0 ? bq : (z == 1 ? bk : bv);

  __shared__ f16 As[2][128 * 40];
  __shared__ f16 Bs[2][128 * 40];
  const int t = threadIdx.x;
  const int lane = t & 63, wid = t >> 6;
  const int wm = wid >> 1, wn = wid & 1;
  const int lr = lane & 15, lg = lane >> 4;
  const int bm = blockIdx.y * 128, bn = blockIdx.x * 128;

  f32x4 acc[4][4] = {};

  const int r0s = t >> 2, g0 = (t & 3) * 8;
  const f16* gA0 = &A[(size_t)(bm + r0s) * 1024 + g0];
  const f16* gA1 = gA0 + (size_t)64 * 1024;
  const f16* gB0 = &BT[(size_t)(bn + r0s) * 1024 + g0];
  const f16* gB1 = gB0 + (size_t)64 * 1024;
  const int dst0 = r0s * 40 + g0, dst1 = (r0s + 64) * 40 + g0;

  int4 sA0, sA1, sB0, sB1;
  auto GLOAD = [&](int k0) {
    sA0 = *reinterpret_cast<const int4*>(gA0 + k0);
    sA1 = *reinterpret_cast<const int4*>(gA1 + k0);
    sB0 = *reinterpret_cast<const int4*>(gB0 + k0);
    sB1 = *reinterpret_cast<const int4*>(gB1 + k0);
  };
  auto DSW = [&](int bb) {
    *reinterpret_cast<int4*>(&As[bb][dst0]) = sA0;
    *reinterpret_cast<int4*>(&As[bb][dst1]) = sA1;
    *reinterpret_cast<int4*>(&Bs[bb][dst0]) = sB0;
    *reinterpret_cast<int4*>(&Bs[bb][dst1]) = sB1;
  };
  auto LDF = [&](int bb, int kk, f16x4 (&af)[4], f16x4 (&bf)[4]) {
#pragma unroll
    for (int mf = 0; mf < 4; ++mf)
      af[mf] = *reinterpret_cast<const f16x4*>(&As[bb][(wm * 64 + mf * 16 + lr) * 40 + kk * 16 + 4 * lg]);
#pragma unroll
    for (int nf = 0; nf < 4; ++nf)
      bf[nf] = *reinterpret_cast<const f16x4*>(&Bs[bb][(wn * 64 + nf * 16 + lr) * 40 + kk * 16 + 4 * lg]);
  };

  GLOAD(0);
  DSW(0);
  LBAR();
  if (z != 2) {
#pragma unroll 1
    for (int k = 0; k < 32; ++k) {
      if (k + 1 < 32) GLOAD((k + 1) * 32);
#pragma unroll
      for (int kk = 0; kk < 2; ++kk) {
        f16x4 af[4], bf[4];
        LDF(k & 1, kk, af, bf);
#pragma unroll
        for (int mf = 0; mf < 4; ++mf)
#pragma unroll
          for (int nf = 0; nf < 4; ++nf)
            acc[mf][nf] = __builtin_amdgcn_mfma_f32_16x16x16f16(af[mf], bf[nf], acc[mf][nf], 0, 0, 0);
      }
      if (k + 1 < 32) {
        DSW((k + 1) & 1);
        LBAR();
      }
    }
  } else {
#pragma unroll 1
    for (int k = 0; k < 32; ++k) {
      if (k + 1 < 32) GLOAD((k + 1) * 32);
#pragma unroll
      for (int kk = 0; kk < 2; ++kk) {
        f16x4 af[4], bf[4];
        LDF(k & 1, kk, af, bf);
#pragma unroll
        for (int mf = 0; mf < 4; ++mf)
#pragma unroll
          for (int nf = 0; nf < 4; ++nf)
            acc[mf][nf] = __builtin_amdgcn_mfma_f32_16x16x16f16(bf[nf], af[mf], acc[mf][nf], 0, 0, 0);
      }
      if (k + 1 < 32) {
        DSW((k + 1) & 1);
        LBAR();
      }
    }
  }

  if (z != 2) {
    const float scale = z == 0 ? 0.125f : 1.f;
    f16* outp = z == 0 ? qb : kb;
#pragma unroll
    for (int mf = 0; mf < 4; ++mf)
#pragma unroll
      for (int nf = 0; nf < 4; ++nf)
#pragma unroll
        for (int i = 0; i < 4; ++i) {
          const int mrow = bm + wm * 64 + mf * 16 + 4 * lg + i;
          const int ncol = bn + wn * 64 + nf * 16 + lr;
          const float v = (acc[mf][nf][i] + bias[ncol]) * scale;
          const int b = mrow >> 11, s = mrow & 2047;
          const int h = ncol >> 6, d = ncol & 63;
          outp[((size_t)(b * N_HEADS + h) * S_LEN + s) * D_K + d] = (f16)v;
        }
  } else {
#pragma unroll
    for (int mf = 0; mf < 4; ++mf)
#pragma unroll
      for (int nf = 0; nf < 4; ++nf)
#pragma unroll
        for (int i = 0; i < 4; ++i) {
          const int srow = bm + wm * 64 + mf * 16 + lr;
          const int dcol = bn + wn * 64 + nf * 16 + 4 * lg + i;
          const float v = acc[mf][nf][i] + bias[dcol];
          const int b = srow >> 11, s = srow & 2047;
          const int h = dcol >> 6, d = dcol & 63;
          vTb[((size_t)(b * N_HEADS + h) * D_K + d) * S_LEN + s] = (f16)v;
        }
  }
}

// ---------------- output GEMM: out[8192][1024] = ctx(f16) @ WoT + bo (fp32 out) ----------------
__global__ __launch_bounds__(256, 3) void gemmO(const f16* __restrict__ A, const f16* __restrict__ BT,
                                                const float* __restrict__ bias, float* __restrict__ outp) {
  __shared__ f16 As[2][128 * 40];
  __shared__ f16 Bs[2][128 * 40];
  const int t = threadIdx.x;
  const int lane = t & 63, wid = t >> 6;
  const int wm = wid >> 1, wn = wid & 1;
  const int lr = lane & 15, lg = lane >> 4;
  const int bm = blockIdx.y * 128, bn = blockIdx.x * 128;

  f32x4 acc[4][4] = {};

  const int r0s = t >> 2, g0 = (t & 3) * 8;
  const f16* gA0 = &A[(size_t)(bm + r0s) * 1024 + g0];
  const f16* gA1 = gA0 + (size_t)64 * 1024;
  const f16* gB0 = &BT[(size_t)(bn + r0s) * 1024 + g0];
  const f16* gB1 = gB0 + (size_t)64 * 1024;
  const int dst0 = r0s * 40 + g0, dst1 = (r0s + 64) * 40 + g0;

  int4 sA0, sA1, sB0, sB1;
  auto GLOAD = [&](int k0) {
    sA0 = *reinterpret_cast<const int4*>(gA0 + k0);
    sA1 = *reinterpret_cast<const int4*>(gA1 + k0);
    sB0 = *reinterpret_cast<const int4*>(gB0 + k0);
    sB1 = *reinterpret_cast<const int4*>(gB1 + k0);
  };
  auto DSW = [&](int bb) {
    *reinterpret_cast<int4*>(&As[bb][dst0]) = sA0;
    *reinterpret_cast<int4*>(&As[bb][dst1]) = sA1;
    *reinterpret_cast<int4*>(&Bs[bb][dst0]) = sB0;
    *reinterpret_cast<int4*>(&Bs[bb][dst1]) = sB1;
  };

  GLOAD(0);
  DSW(0);
  LBAR();
#pragma unroll 1
  for (int k = 0; k < 32; ++k) {
    if (k + 1 < 32) GLOAD((k + 1) * 32);
#pragma unroll
    for (int kk = 0; kk < 2; ++kk) {
      f16x4 af[4], bf[4];
#pragma unroll
      for (int mf = 0; mf < 4; ++mf)
        af[mf] = *reinterpret_cast<const f16x4*>(&As[k & 1][(wm * 64 + mf * 16 + lr) * 40 + kk * 16 + 4 * lg]);
#pragma unroll
      for (int nf = 0; nf < 4; ++nf)
        bf[nf] = *reinterpret_cast<const f16x4*>(&Bs[k & 1][(wn * 64 + nf * 16 + lr) * 40 + kk * 16 + 4 * lg]);
#pragma unroll
      for (int mf = 0; mf < 4; ++mf)
#pragma unroll
        for (int nf = 0; nf < 4; ++nf)
          acc[mf][nf] = __builtin_amdgcn_mfma_f32_16x16x16f16(af[mf], bf[nf], acc[mf][nf], 0, 0, 0);
    }
    if (k + 1 < 32) {
      DSW((k + 1) & 1);
      LBAR();
    }
  }

#pragma unroll
  for (int mf = 0; mf < 4; ++mf)
#pragma unroll
    for (int nf = 0; nf < 4; ++nf)
#pragma unroll
      for (int i = 0; i < 4; ++i) {
        const int mrow = bm + wm * 64 + mf * 16 + 4 * lg + i;
        const int ncol = bn + wn * 64 + nf * 16 + lr;
        outp[(size_t)mrow * D_MODEL + ncol] = acc[mf][nf][i] + bias[ncol];
      }
}

// ---------------- two-sweep fused attention: sums, then normalized direct write + PV ----------
// Sweep 1: pipelined QK^T + rel + exp -> per-row sums (no stores, no V).
// Sweep 2: recompute scores (inputs L2-hot), normalize IN-LANE (lane owns q-row = lr),
//          NT-write f32 attn directly, PV with normalized P -> ctx (no inv shuffles anywhere).
__global__ __launch_bounds__(256, 3) void attn_fused2(const f16* __restrict__ qg, const f16* __restrict__ kg,
                                                      const f16* __restrict__ vTg, const f16* __restrict__ rel16,
                                                      const int* __restrict__ mask, float* __restrict__ attn_out,
                                                      f16* __restrict__ ctx) {
  const int b = blockIdx.x & 3, qt = blockIdx.x >> 2;
  const int h = blockIdx.y;
  const int t = threadIdx.x, w = t >> 6, lane = t & 63;
  const int lr = lane & 15, lg = lane >> 4;
  const int lr7 = lr & 7;
  const int Ld8 = lane >> 3, Lm8 = lane & 7;

  __shared__ f16 Kc[2][64 * 64];
  __shared__ f16 Vc[2][64 * 64];
  __shared__ f16 Rc[2][64 * 64];
  __shared__ f16 maskh[S_LEN];

  for (int i = t; i < S_LEN; i += 256) maskh[i] = mask[b * S_LEN + i] ? (f16)EXP_NEG8 : (f16)0.f;

  const size_t bh = (size_t)(b * N_HEADS + h);
  const f16* qbh = qg + bh * S_LEN * D_K;
  const f16* kbh = kg + bh * S_LEN * D_K;
  const f16* vbh = vTg + bh * (size_t)D_K * S_LEN;
  const f16* relh = rel16 + (size_t)h * S_LEN * S_LEN;

  const int r0 = qt * 64 + w * 16;
  const int myq = r0 + lr;
  float* attnq = attn_out + bh * (size_t)S_LEN * S_LEN + (size_t)myq * S_LEN;

  const int row0 = w * 16 + Ld8;
  const int row1 = row0 + 8;
  const f16* gK0 = kbh + (size_t)row0 * D_K + Lm8 * 8;
  const f16* gK1 = kbh + (size_t)row1 * D_K + Lm8 * 8;
  const f16* gV0 = vbh + (size_t)row0 * S_LEN + Lm8 * 8;
  const f16* gV1 = vbh + (size_t)row1 * S_LEN + Lm8 * 8;
  const f16* gR0 = relh + (size_t)(qt * 64 + row0) * S_LEN + Lm8 * 8;
  const f16* gR1 = relh + (size_t)(qt * 64 + row1) * S_LEN + Lm8 * 8;
  const int dK0 = row0 * 64 + ((Lm8 ^ Ld8) << 3);
  const int dK1 = row1 * 64 + ((Lm8 ^ Ld8) << 3);
  const int dVR0 = row0 * 64 + ((((Lm8 << 1) ^ (Ld8 << 1)) & 15) << 2);
  const int dVR1 = row1 * 64 + ((((Lm8 << 1) ^ (Ld8 << 1)) & 15) << 2);

  f16x8 qf8[2];
#pragma unroll
  for (int p = 0; p < 2; ++p)
    qf8[p] = *reinterpret_cast<const f16x8*>(&qbh[(size_t)myq * D_K + 32 * p + 8 * lg]);

  int4 sK0, sK1, sV0, sV1, sR0, sR1;
  auto GK = [&](int c0) {
    sK0 = *reinterpret_cast<const int4*>(gK0 + (size_t)c0 * D_K);
    sK1 = *reinterpret_cast<const int4*>(gK1 + (size_t)c0 * D_K);
  };
  auto GV = [&](int c0) {
    sV0 = *reinterpret_cast<const int4*>(gV0 + c0);
    sV1 = *reinterpret_cast<const int4*>(gV1 + c0);
  };
  auto GR = [&](int c0) {
    sR0 = *reinterpret_cast<const int4*>(gR0 + c0);
    sR1 = *reinterpret_cast<const int4*>(gR1 + c0);
  };
  auto DSW1 = [&](int bb) {
    *reinterpret_cast<int4*>(&Kc[bb][dK0]) = sK0;
    *reinterpret_cast<int4*>(&Kc[bb][dK1]) = sK1;
    *reinterpret_cast<int4*>(&Rc[bb][dVR0]) = sR0;
    *reinterpret_cast<int4*>(&Rc[bb][dVR1]) = sR1;
  };
  auto DSW2 = [&](int bb) {
    *reinterpret_cast<int4*>(&Kc[bb][dK0]) = sK0;
    *reinterpret_cast<int4*>(&Kc[bb][dK1]) = sK1;
    *reinterpret_cast<int4*>(&Vc[bb][dVR0]) = sV0;
    *reinterpret_cast<int4*>(&Vc[bb][dVR1]) = sV1;
    *reinterpret_cast<int4*>(&Rc[bb][dVR0]) = sR0;
    *reinterpret_cast<int4*>(&Rc[bb][dVR1]) = sR1;
  };

  auto SCORES = [&](int bb, f32x4 (&sc)[4]) {
#pragma unroll
    for (int p = 0; p < 2; ++p) {
      const f16x4 qlo = __builtin_shufflevector(qf8[p], qf8[p], 0, 1, 2, 3);
      const f16x4 qhi = __builtin_shufflevector(qf8[p], qf8[p], 4, 5, 6, 7);
#pragma unroll
      for (int j = 0; j < 4; ++j) {
        const f16x8 kv = *reinterpret_cast<const f16x8*>(
            &Kc[bb][(16 * j + lr) * 64 + (((4 * p + lg) ^ lr7) << 3)]);
        sc[j] = __builtin_amdgcn_mfma_f32_16x16x16f16(
            __builtin_shufflevector(kv, kv, 0, 1, 2, 3), qlo, sc[j], 0, 0, 0);
        sc[j] = __builtin_amdgcn_mfma_f32_16x16x16f16(
            __builtin_shufflevector(kv, kv, 4, 5, 6, 7), qhi, sc[j], 0, 0, 0);
      }
    }
  };

  // ---- sweep 1: row sums ----
  float sum = 0.f;
  GK(0);
  GR(0);
  DSW1(0);
  LBAR();
#pragma unroll 1
  for (int c = 0; c < 32; ++c) {
    if (c + 1 < 32) {
      GK((c + 1) * 64);
      GR((c + 1) * 64);
    }
    const int bb = c & 1;
    f32x4 sc[4] = {};
    SCORES(bb, sc);
#pragma unroll
    for (int j = 0; j < 4; ++j) {
      const int sgp = ((4 * j + lg) ^ (lr7 << 1)) & 15;
      const f16x4 rl = *reinterpret_cast<const f16x4*>(&Rc[bb][(w * 16 + lr) * 64 + (sgp << 2)]);
      const int col = c * 64 + 16 * j + 4 * lg;
      const f16x4 mh = *reinterpret_cast<const f16x4*>(&maskh[col]);
      sum += __expf(sc[j][0] + (float)rl[0]) * (float)mh[0] +
             __expf(sc[j][1] + (float)rl[1]) * (float)mh[1] +
             __expf(sc[j][2] + (float)rl[2]) * (float)mh[2] +
             __expf(sc[j][3] + (float)rl[3]) * (float)mh[3];
    }
    if (c + 1 < 32) {
      DSW1((c + 1) & 1);
      LBAR();
    }
  }
  sum += __shfl_xor(sum, 16, 64);
  sum += __shfl_xor(sum, 32, 64);
  const float inv = 1.f / sum;  // lane-local: this lane's q-row is myq = r0 + lr

  // ---- sweep 2: normalized attn write + PV ----
  f32x4 pv[4] = {};
  GK(0);
  GV(0);
  GR(0);
  DSW2(0);   // writes buf0; any wave still in sweep-1 c=31 only reads buf1 -> safe
  LBAR();
#pragma unroll 1
  for (int c = 0; c < 32; ++c) {
    if (c + 1 < 32) {
      GK((c + 1) * 64);
      GV((c + 1) * 64);
      GR((c + 1) * 64);
    }
    const int bb = c & 1;
    f32x4 sc[4] = {};
    SCORES(bb, sc);
#pragma unroll
    for (int j = 0; j < 4; ++j) {
      const int sgp = ((4 * j + lg) ^ (lr7 << 1)) & 15;
      const f16x4 rl = *reinterpret_cast<const f16x4*>(&Rc[bb][(w * 16 + lr) * 64 + (sgp << 2)]);
      const int col = c * 64 + 16 * j + 4 * lg;
      const f16x4 mh = *reinterpret_cast<const f16x4*>(&maskh[col]);
      const float a0 = __expf(sc[j][0] + (float)rl[0]) * (float)mh[0] * inv;
      const float a1 = __expf(sc[j][1] + (float)rl[1]) * (float)mh[1] * inv;
      const float a2 = __expf(sc[j][2] + (float)rl[2]) * (float)mh[2] * inv;
      const float a3 = __expf(sc[j][3] + (float)rl[3]) * (float)mh[3] * inv;
      f32x4 av = {a0, a1, a2, a3};
      __builtin_nontemporal_store(av, reinterpret_cast<f32x4*>(&attnq[col]));
      f16x4 pf;
      pf.x = (f16)a0; pf.y = (f16)a1; pf.z = (f16)a2; pf.w = (f16)a3;
#pragma unroll
      for (int nf = 0; nf < 4; ++nf) {
        const f16x4 vf = *reinterpret_cast<const f16x4*>(&Vc[bb][(nf * 16 + lr) * 64 + (sgp << 2)]);
        pv[nf] = __builtin_amdgcn_mfma_f32_16x16x16f16(pf, vf, pv[nf], 0, 0, 0);
      }
    }
    if (c + 1 < 32) {
      DSW2((c + 1) & 1);
      LBAR();
    }
  }

#pragma unroll
  for (int nf = 0; nf < 4; ++nf)
#pragma unroll
    for (int i = 0; i < 4; ++i)
      ctx[(size_t)(b * S_LEN + r0 + 4 * lg + i) * D_MODEL + h * D_K + nf * 16 + lr] =
          (f16)pv[nf][i];
}

// ---------------- fallback: single-pass, no staging, rel f32, attn written directly ----------------
__global__ __launch_bounds__(256) void attn_single(const f16* __restrict__ qg, const f16* __restrict__ kg,
                                                   const f16* __restrict__ vTg, const float* __restrict__ relp,
                                                   const int* __restrict__ mask, float* __restrict__ attn_out,
                                                   f16* __restrict__ ctx) {
  const int b = blockIdx.x & 3, qt = blockIdx.x >> 2;
  const int h = blockIdx.y;
  const int t = threadIdx.x, w = t >> 6, lane = t & 63;
  const int lr = lane & 15, lg = lane >> 4;
  __shared__ float mask_f[S_LEN];

  for (int i = t; i < S_LEN; i += 256) mask_f[i] = mask[b * S_LEN + i] ? EXP_NEG8 : 0.f;
  __syncthreads();

  const size_t bh = (size_t)(b * N_HEADS + h);
  const f16* qbh = qg + bh * S_LEN * D_K;
  const f16* kbh = kg + bh * S_LEN * D_K;
  const f16* vbh = vTg + bh * (size_t)D_K * S_LEN;

  const int r0 = qt * 64 + w * 16;
  const int myq = r0 + lr;

  const float* relq32 = relp + (size_t)h * S_LEN * S_LEN + (size_t)myq * S_LEN;
  float* attnq = attn_out + bh * (size_t)S_LEN * S_LEN + (size_t)myq * S_LEN;

  f16x8 qf8[2];
#pragma unroll
  for (int p = 0; p < 2; ++p)
    qf8[p] = *reinterpret_cast<const f16x8*>(&qbh[(size_t)myq * D_K + 32 * p + 8 * lg]);

  float sum = 0.f;
  f32x4 pv[4] = {};

  auto CH = [&](int c0) {
    f32x4 sc[4] = {};
#pragma unroll
    for (int p = 0; p < 2; ++p) {
      const f16x4 qlo = __builtin_shufflevector(qf8[p], qf8[p], 0, 1, 2, 3);
      const f16x4 qhi = __builtin_shufflevector(qf8[p], qf8[p], 4, 5, 6, 7);
#pragma unroll
      for (int j = 0; j < 4; ++j) {
        const f16x8 kv = *reinterpret_cast<const f16x8*>(
            &kbh[(size_t)(c0 + 16 * j + lr) * D_K + 32 * p + 8 * lg]);
        sc[j] = __builtin_amdgcn_mfma_f32_16x16x16f16(
            __builtin_shufflevector(kv, kv, 0, 1, 2, 3), qlo, sc[j], 0, 0, 0);
        sc[j] = __builtin_amdgcn_mfma_f32_16x16x16f16(
            __builtin_shufflevector(kv, kv, 4, 5, 6, 7), qhi, sc[j], 0, 0, 0);
      }
    }
#pragma unroll
    for (int j = 0; j < 4; ++j) {
      const int col = c0 + 16 * j + 4 * lg;
      const float4 rl = *reinterpret_cast<const float4*>(&relq32[col]);
      const float4 mk = *reinterpret_cast<const float4*>(&mask_f[col]);
      const float a0 = __expf(sc[j][0] + rl.x) * mk.x;
      const float a1 = __expf(sc[j][1] + rl.y) * mk.y;
      const float a2 = __expf(sc[j][2] + rl.z) * mk.z;
      const float a3 = __expf(sc[j][3] + rl.w) * mk.w;
      sum += a0 + a1 + a2 + a3;
      f16x4 pf;
      pf.x = (f16)a0; pf.y = (f16)a1; pf.z = (f16)a2; pf.w = (f16)a3;
      *reinterpret_cast<float4*>(&attnq[col]) = make_float4(a0, a1, a2, a3);
#pragma unroll
      for (int nf = 0; nf < 4; ++nf) {
        const f16x4 vf = *reinterpret_cast<const f16x4*>(&vbh[(size_t)(nf * 16 + lr) * S_LEN + col]);
        pv[nf] = __builtin_amdgcn_mfma_f32_16x16x16f16(pf, vf, pv[nf], 0, 0, 0);
      }
    }
  };

#pragma unroll 1
  for (int c0 = 0; c0 < S_LEN; c0 += 64) CH(c0);

  sum += __shfl_xor(sum, 16, 64);
  sum += __shfl_xor(sum, 32, 64);
  const float inv = 1.f / sum;

  float ivr[4];
#pragma unroll
  for (int i = 0; i < 4; ++i) ivr[i] = __shfl(inv, 4 * lg + i, 64);
#pragma unroll
  for (int nf = 0; nf < 4; ++nf)
#pragma unroll
    for (int i = 0; i < 4; ++i)
      ctx[(size_t)(b * S_LEN + r0 + 4 * lg + i) * D_MODEL + h * D_K + nf * 16 + lr] =
          (f16)(pv[nf][i] * ivr[i]);

  float4* aw4 = reinterpret_cast<float4*>(attn_out + bh * (size_t)S_LEN * S_LEN + (size_t)r0 * S_LEN);
#pragma unroll 1
  for (int it = 0; it < 128; it += 4) {
#pragma unroll
    for (int u = 0; u < 4; ++u) {
      const float iv = __shfl(inv, (it + u) >> 3, 64);
      float4 v = aw4[(it + u) * 64 + lane];
      v.x *= iv; v.y *= iv; v.z *= iv; v.w *= iv;
      aw4[(it + u) * 64 + lane] = v;
    }
  }
}

extern "C" void kernel_launch(void* const* d_in, const int* in_sizes, int n_in,
                              void* d_out, int out_size, void* d_ws, size_t ws_size,
                              hipStream_t stream) {
  const float* Q    = (const float*)d_in[0];
  const float* K    = (const float*)d_in[1];
  const float* V    = (const float*)d_in[2];
  const int*   mask = (const int*)d_in[3];
  const float* rel  = (const float*)d_in[4];
  const float* Wq   = (const float*)d_in[5];
  const float* bq   = (const float*)d_in[6];
  const float* Wk   = (const float*)d_in[7];
  const float* bk   = (const float*)d_in[8];
  const float* Wv   = (const float*)d_in[9];
  const float* bv   = (const float*)d_in[10];
  const float* Wo   = (const float*)d_in[11];
  const float* bo   = (const float*)d_in[12];

  char* wsb = (char*)d_ws;
  const size_t XSZ = (size_t)BATCH * S_LEN * D_MODEL * sizeof(f16);  // 16.78 MB
  const size_t WSZ = (size_t)D_MODEL * D_MODEL * sizeof(f16);        // 2 MB
  f16* Qh  = (f16*)(wsb);
  f16* Kh  = (f16*)(wsb + XSZ);
  f16* Vh  = (f16*)(wsb + 2 * XSZ);
  f16* WqT = (f16*)(wsb + 3 * XSZ);
  f16* WkT = (f16*)(wsb + 3 * XSZ + WSZ);
  f16* WvT = (f16*)(wsb + 3 * XSZ + 2 * WSZ);
  f16* WoT = (f16*)(wsb + 3 * XSZ + 3 * WSZ);
  f16* qb  = (f16*)(wsb + 3 * XSZ + 4 * WSZ);
  f16* kb  = (f16*)(wsb + 4 * XSZ + 4 * WSZ);
  f16* vTb = (f16*)(wsb + 5 * XSZ + 4 * WSZ);
  f16* ctx = (f16*)(wsb + 6 * XSZ + 4 * WSZ);

  const size_t BASE  = 7 * XSZ + 4 * WSZ;                                 // 125.8 MB
  const size_t RELSZ = (size_t)N_HEADS * S_LEN * S_LEN * sizeof(f16);     // 134.2 MB
  f16* rel16 = (f16*)(wsb + BASE);
  const bool r16 = ws_size >= BASE + RELSZ;

  float* out0 = (float*)d_out;
  float* attn = out0 + (size_t)BATCH * S_LEN * D_MODEL;

  const int n4 = BATCH * S_LEN * D_MODEL / 4;  // 2097152
  cvt3<<<dim3(n4 / 256, 3), 256, 0, stream>>>(Q, K, V, Qh, Kh, Vh, n4);
  wtrans4<<<dim3(32, 32, 4), dim3(32, 8), 0, stream>>>(Wq, Wk, Wv, Wo, WqT, WkT, WvT, WoT);
  if (r16) {
    const int nr4 = N_HEADS * S_LEN * S_LEN / 4;  // 16,777,216
    cvt_f32_f16<<<dim3(nr4 / 256), 256, 0, stream>>>(rel, rel16, nr4);
  }

  gemmQKV<<<dim3(8, 64, 3), 256, 0, stream>>>(Qh, Kh, Vh, WqT, WkT, WvT, bq, bk, bv, qb, kb, vTb);

  if (r16) {
    attn_fused2<<<dim3(BATCH * (S_LEN / 64), N_HEADS), 256, 0, stream>>>(qb, kb, vTb, rel16, mask,
                                                                         attn, ctx);
  } else {
    attn_single<<<dim3(BATCH * (S_LEN / 64), N_HEADS), 256, 0, stream>>>(qb, kb, vTb, rel, mask,
                                                                         attn, ctx);
  }

  gemmO<<<dim3(8, 64), 256, 0, stream>>>(ctx, WoT, bo, out0);
}

// Round 14
// 673.827 us; speedup vs baseline: 1.3722x; 1.0300x over previous
//
#include <hip/hip_runtime.h>
#include <hip/hip_fp16.h>

typedef _Float16 f16;
typedef __attribute__((ext_vector_type(4))) _Float16 f16x4;
typedef __attribute__((ext_vector_type(8))) _Float16 f16x8;
typedef __attribute__((ext_vector_type(4))) float f32x4;

#define S_LEN 2048
#define D_MODEL 1024
#define N_HEADS 16
#define D_K 64
#define BATCH 4

// exp(-8): folded into mask so unnormalized e = exp(score+rel-8)*mask stays small.
// Common to every unmasked column -> cancels exactly in e/sum (f16 quantization included).
#define EXP_NEG8 3.35462627903e-4f

// lgkmcnt-only barrier: does NOT drain vmcnt, so staged global loads stay in flight across it.
#define LBAR() do { asm volatile("s_waitcnt lgkmcnt(0)" ::: "memory"); \
                    __builtin_amdgcn_s_barrier(); } while (0)

// ---------------- fp32 -> fp16 convert (vectorized) ----------------
__global__ void cvt_f32_f16(const float* __restrict__ src, f16* __restrict__ dst, int n4) {
  int i = blockIdx.x * blockDim.x + threadIdx.x;
  if (i < n4) {
    const float4 v = reinterpret_cast<const float4*>(src)[i];
    f16x4 h;
    h.x = (f16)v.x; h.y = (f16)v.y; h.z = (f16)v.z; h.w = (f16)v.w;
    reinterpret_cast<f16x4*>(dst)[i] = h;
  }
}

// batched Q/K/V convert (one launch)
__global__ void cvt3(const float* __restrict__ s0, const float* __restrict__ s1,
                     const float* __restrict__ s2, f16* __restrict__ d0, f16* __restrict__ d1,
                     f16* __restrict__ d2, int n4) {
  const float* s = blockIdx.y == 0 ? s0 : (blockIdx.y == 1 ? s1 : s2);
  f16* d = blockIdx.y == 0 ? d0 : (blockIdx.y == 1 ? d1 : d2);
  int i = blockIdx.x * blockDim.x + threadIdx.x;
  if (i < n4) {
    const float4 v = reinterpret_cast<const float4*>(s)[i];
    f16x4 h;
    h.x = (f16)v.x; h.y = (f16)v.y; h.z = (f16)v.z; h.w = (f16)v.w;
    reinterpret_cast<f16x4*>(d)[i] = h;
  }
}

// ---------------- weight transpose + convert (batched over 4 weights) ----------------
__global__ void wtrans4(const float* __restrict__ W0, const float* __restrict__ W1,
                        const float* __restrict__ W2, const float* __restrict__ W3,
                        f16* __restrict__ T0, f16* __restrict__ T1, f16* __restrict__ T2,
                        f16* __restrict__ T3) {
  const float* W = blockIdx.z == 0 ? W0 : (blockIdx.z == 1 ? W1 : (blockIdx.z == 2 ? W2 : W3));
  f16* WT = blockIdx.z == 0 ? T0 : (blockIdx.z == 1 ? T1 : (blockIdx.z == 2 ? T2 : T3));
  __shared__ float tile[32][33];
  const int n0 = blockIdx.x * 32, k0 = blockIdx.y * 32;
  const int tx = threadIdx.x, ty = threadIdx.y;  // block (32,8)
#pragma unroll
  for (int i = 0; i < 4; ++i)
    tile[ty + i * 8][tx] = W[(size_t)(k0 + ty + i * 8) * D_MODEL + n0 + tx];
  __syncthreads();
#pragma unroll
  for (int i = 0; i < 4; ++i)
    WT[(size_t)(n0 + ty + i * 8) * D_MODEL + k0 + tx] = (f16)tile[tx][ty + i * 8];
}

// ---------------- merged QKV projection GEMM (grid.z selects Q/K/V) ----------------
__global__ __launch_bounds__(256, 3) void gemmQKV(const f16* __restrict__ Qh, const f16* __restrict__ Kh,
                                                  const f16* __restrict__ Vh, const f16* __restrict__ WqT,
                                                  const f16* __restrict__ WkT, const f16* __restrict__ WvT,
                                                  const float* __restrict__ bq, const float* __restrict__ bk,
                                                  const float* __restrict__ bv, f16* __restrict__ qb,
                                                  f16* __restrict__ kb, f16* __restrict__ vTb) {
  const int z = blockIdx.z;
  const f16* A = z == 0 ? Qh : (z == 1 ? Kh : Vh);
  const f16* BT = z == 0 ? WqT : (z == 1 ? WkT : WvT);
  const float* bias = z == 0 ? bq : (z == 1 ? bk : bv);

  __shared__ f16 As[2][128 * 40];
  __shared__ f16 Bs[2][128 * 40];
  const int t = threadIdx.x;
  const int lane = t & 63, wid = t >> 6;
  const int wm = wid >> 1, wn = wid & 1;
  const int lr = lane & 15, lg = lane >> 4;
  const int bm = blockIdx.y * 128, bn = blockIdx.x * 128;

  f32x4 acc[4][4] = {};

  const int r0s = t >> 2, g0 = (t & 3) * 8;
  const f16* gA0 = &A[(size_t)(bm + r0s) * 1024 + g0];
  const f16* gA1 = gA0 + (size_t)64 * 1024;
  const f16* gB0 = &BT[(size_t)(bn + r0s) * 1024 + g0];
  const f16* gB1 = gB0 + (size_t)64 * 1024;
  const int dst0 = r0s * 40 + g0, dst1 = (r0s + 64) * 40 + g0;

  int4 sA0, sA1, sB0, sB1;
  auto GLOAD = [&](int k0) {
    sA0 = *reinterpret_cast<const int4*>(gA0 + k0);
    sA1 = *reinterpret_cast<const int4*>(gA1 + k0);
    sB0 = *reinterpret_cast<const int4*>(gB0 + k0);
    sB1 = *reinterpret_cast<const int4*>(gB1 + k0);
  };
  auto DSW = [&](int bb) {
    *reinterpret_cast<int4*>(&As[bb][dst0]) = sA0;
    *reinterpret_cast<int4*>(&As[bb][dst1]) = sA1;
    *reinterpret_cast<int4*>(&Bs[bb][dst0]) = sB0;
    *reinterpret_cast<int4*>(&Bs[bb][dst1]) = sB1;
  };
  auto LDF = [&](int bb, int kk, f16x4 (&af)[4], f16x4 (&bf)[4]) {
#pragma unroll
    for (int mf = 0; mf < 4; ++mf)
      af[mf] = *reinterpret_cast<const f16x4*>(&As[bb][(wm * 64 + mf * 16 + lr) * 40 + kk * 16 + 4 * lg]);
#pragma unroll
    for (int nf = 0; nf < 4; ++nf)
      bf[nf] = *reinterpret_cast<const f16x4*>(&Bs[bb][(wn * 64 + nf * 16 + lr) * 40 + kk * 16 + 4 * lg]);
  };

  GLOAD(0);
  DSW(0);
  LBAR();
  if (z != 2) {
#pragma unroll 1
    for (int k = 0; k < 32; ++k) {
      if (k + 1 < 32) GLOAD((k + 1) * 32);
#pragma unroll
      for (int kk = 0; kk < 2; ++kk) {
        f16x4 af[4], bf[4];
        LDF(k & 1, kk, af, bf);
#pragma unroll
        for (int mf = 0; mf < 4; ++mf)
#pragma unroll
          for (int nf = 0; nf < 4; ++nf)
            acc[mf][nf] = __builtin_amdgcn_mfma_f32_16x16x16f16(af[mf], bf[nf], acc[mf][nf], 0, 0, 0);
      }
      if (k + 1 < 32) {
        DSW((k + 1) & 1);
        LBAR();
      }
    }
  } else {
#pragma unroll 1
    for (int k = 0; k < 32; ++k) {
      if (k + 1 < 32) GLOAD((k + 1) * 32);
#pragma unroll
      for (int kk = 0; kk < 2; ++kk) {
        f16x4 af[4], bf[4];
        LDF(k & 1, kk, af, bf);
#pragma unroll
        for (int mf = 0; mf < 4; ++mf)
#pragma unroll
          for (int nf = 0; nf < 4; ++nf)
            acc[mf][nf] = __builtin_amdgcn_mfma_f32_16x16x16f16(bf[nf], af[mf], acc[mf][nf], 0, 0, 0);
      }
      if (k + 1 < 32) {
        DSW((k + 1) & 1);
        LBAR();
      }
    }
  }

  if (z != 2) {
    const float scale = z == 0 ? 0.125f : 1.f;
    f16* outp = z == 0 ? qb : kb;
#pragma unroll
    for (int mf = 0; mf < 4; ++mf)
#pragma unroll
      for (int nf = 0; nf < 4; ++nf)
#pragma unroll
        for (int i = 0; i < 4; ++i) {
          const int mrow = bm + wm * 64 + mf * 16 + 4 * lg + i;
          const int ncol = bn + wn * 64 + nf * 16 + lr;
          const float v = (acc[mf][nf][i] + bias[ncol]) * scale;
          const int b = mrow >> 11, s = mrow & 2047;
          const int h = ncol >> 6, d = ncol & 63;
          outp[((size_t)(b * N_HEADS + h) * S_LEN + s) * D_K + d] = (f16)v;
        }
  } else {
#pragma unroll
    for (int mf = 0; mf < 4; ++mf)
#pragma unroll
      for (int nf = 0; nf < 4; ++nf)
#pragma unroll
        for (int i = 0; i < 4; ++i) {
          const int srow = bm + wm * 64 + mf * 16 + lr;
          const int dcol = bn + wn * 64 + nf * 16 + 4 * lg + i;
          const float v = acc[mf][nf][i] + bias[dcol];
          const int b = srow >> 11, s = srow & 2047;
          const int h = dcol >> 6, d = dcol & 63;
          vTb[((size_t)(b * N_HEADS + h) * D_K + d) * S_LEN + s] = (f16)v;
        }
  }
}

// ---------------- output GEMM: out[8192][1024] = ctx(f16) @ WoT + bo (fp32 out) ----------------
__global__ __launch_bounds__(256, 3) void gemmO(const f16* __restrict__ A, const f16* __restrict__ BT,
                                                const float* __restrict__ bias, float* __restrict__ outp) {
  __shared__ f16 As[2][128 * 40];
  __shared__ f16 Bs[2][128 * 40];
  const int t = threadIdx.x;
  const int lane = t & 63, wid = t >> 6;
  const int wm = wid >> 1, wn = wid & 1;
  const int lr = lane & 15, lg = lane >> 4;
  const int bm = blockIdx.y * 128, bn = blockIdx.x * 128;

  f32x4 acc[4][4] = {};

  const int r0s = t >> 2, g0 = (t & 3) * 8;
  const f16* gA0 = &A[(size_t)(bm + r0s) * 1024 + g0];
  const f16* gA1 = gA0 + (size_t)64 * 1024;
  const f16* gB0 = &BT[(size_t)(bn + r0s) * 1024 + g0];
  const f16* gB1 = gB0 + (size_t)64 * 1024;
  const int dst0 = r0s * 40 + g0, dst1 = (r0s + 64) * 40 + g0;

  int4 sA0, sA1, sB0, sB1;
  auto GLOAD = [&](int k0) {
    sA0 = *reinterpret_cast<const int4*>(gA0 + k0);
    sA1 = *reinterpret_cast<const int4*>(gA1 + k0);
    sB0 = *reinterpret_cast<const int4*>(gB0 + k0);
    sB1 = *reinterpret_cast<const int4*>(gB1 + k0);
  };
  auto DSW = [&](int bb) {
    *reinterpret_cast<int4*>(&As[bb][dst0]) = sA0;
    *reinterpret_cast<int4*>(&As[bb][dst1]) = sA1;
    *reinterpret_cast<int4*>(&Bs[bb][dst0]) = sB0;
    *reinterpret_cast<int4*>(&Bs[bb][dst1]) = sB1;
  };

  GLOAD(0);
  DSW(0);
  LBAR();
#pragma unroll 1
  for (int k = 0; k < 32; ++k) {
    if (k + 1 < 32) GLOAD((k + 1) * 32);
#pragma unroll
    for (int kk = 0; kk < 2; ++kk) {
      f16x4 af[4], bf[4];
#pragma unroll
      for (int mf = 0; mf < 4; ++mf)
        af[mf] = *reinterpret_cast<const f16x4*>(&As[k & 1][(wm * 64 + mf * 16 + lr) * 40 + kk * 16 + 4 * lg]);
#pragma unroll
      for (int nf = 0; nf < 4; ++nf)
        bf[nf] = *reinterpret_cast<const f16x4*>(&Bs[k & 1][(wn * 64 + nf * 16 + lr) * 40 + kk * 16 + 4 * lg]);
#pragma unroll
      for (int mf = 0; mf < 4; ++mf)
#pragma unroll
        for (int nf = 0; nf < 4; ++nf)
          acc[mf][nf] = __builtin_amdgcn_mfma_f32_16x16x16f16(af[mf], bf[nf], acc[mf][nf], 0, 0, 0);
    }
    if (k + 1 < 32) {
      DSW((k + 1) & 1);
      LBAR();
    }
  }

#pragma unroll
  for (int mf = 0; mf < 4; ++mf)
#pragma unroll
    for (int nf = 0; nf < 4; ++nf)
#pragma unroll
      for (int i = 0; i < 4; ++i) {
        const int mrow = bm + wm * 64 + mf * 16 + 4 * lg + i;
        const int ncol = bn + wn * 64 + nf * 16 + lr;
        outp[(size_t)mrow * D_MODEL + ncol] = acc[mf][nf][i] + bias[ncol];
      }
}

// ---------------- two-sweep fused attention, QBLK=128 (two 16-row tiles per wave) ----------
// 4 waves / 256 threads; each wave owns q-rows [r0, r0+16) and [r0+64, r0+80).
// Doubles compute per phase against the same per-phase pipeline stall; halves block count.
// LDS 68KB -> 2 blocks/CU. Swizzles identical to the verified QBLK=64 version (row&7 invariant).
__global__ __launch_bounds__(256, 2) void attn_fused2(const f16* __restrict__ qg, const f16* __restrict__ kg,
                                                      const f16* __restrict__ vTg, const f16* __restrict__ rel16,
                                                      const int* __restrict__ mask, float* __restrict__ attn_out,
                                                      f16* __restrict__ ctx) {
  const int b = blockIdx.x & 3, qt = blockIdx.x >> 2;  // qt 0..15
  const int h = blockIdx.y;
  const int t = threadIdx.x, w = t >> 6, lane = t & 63;
  const int lr = lane & 15, lg = lane >> 4;
  const int lr7 = lr & 7;
  const int Ld8 = lane >> 3, Lm8 = lane & 7;

  __shared__ f16 Kc[2][64 * 64];
  __shared__ f16 Vc[2][64 * 64];
  __shared__ f16 Rc[2][128 * 64];
  __shared__ f16 maskh[S_LEN];

  for (int i = t; i < S_LEN; i += 256) maskh[i] = mask[b * S_LEN + i] ? (f16)EXP_NEG8 : (f16)0.f;

  const size_t bh = (size_t)(b * N_HEADS + h);
  const f16* qbh = qg + bh * S_LEN * D_K;
  const f16* kbh = kg + bh * S_LEN * D_K;
  const f16* vbh = vTg + bh * (size_t)D_K * S_LEN;
  const f16* relh = rel16 + (size_t)h * S_LEN * S_LEN;

  const int r0 = qt * 128 + w * 16;     // tile0 rows; tile1 = +64
  const int myq = r0 + lr;
  float* attnq0 = attn_out + bh * (size_t)S_LEN * S_LEN + (size_t)myq * S_LEN;
  float* attnq1 = attnq0 + (size_t)64 * S_LEN;

  // staging rows (tile-local); row&7 == Ld8 for all four
  const int row0 = w * 16 + Ld8;
  const int row1 = row0 + 8;
  const f16* gK0 = kbh + (size_t)row0 * D_K + Lm8 * 8;
  const f16* gK1 = kbh + (size_t)row1 * D_K + Lm8 * 8;
  const f16* gV0 = vbh + (size_t)row0 * S_LEN + Lm8 * 8;
  const f16* gV1 = vbh + (size_t)row1 * S_LEN + Lm8 * 8;
  const f16* gR0 = relh + (size_t)(qt * 128 + row0) * S_LEN + Lm8 * 8;
  const f16* gR1 = relh + (size_t)(qt * 128 + row1) * S_LEN + Lm8 * 8;
  const f16* gR2 = gR0 + (size_t)64 * S_LEN;
  const f16* gR3 = gR1 + (size_t)64 * S_LEN;
  // swizzled LDS dests (f16 idx); +64-row copies keep row&7 -> same swizzle
  const int dK0 = row0 * 64 + ((Lm8 ^ Ld8) << 3);
  const int dK1 = row1 * 64 + ((Lm8 ^ Ld8) << 3);
  const int dVR0 = row0 * 64 + ((((Lm8 << 1) ^ (Ld8 << 1)) & 15) << 2);
  const int dVR1 = row1 * 64 + ((((Lm8 << 1) ^ (Ld8 << 1)) & 15) << 2);
  const int dVR2 = dVR0 + 64 * 64;
  const int dVR3 = dVR1 + 64 * 64;

  // Q fragments for both tiles: qf8x[p] covers dk {32p + 8lg .. +7}
  f16x8 qf80[2], qf81[2];
#pragma unroll
  for (int p = 0; p < 2; ++p) {
    qf80[p] = *reinterpret_cast<const f16x8*>(&qbh[(size_t)myq * D_K + 32 * p + 8 * lg]);
    qf81[p] = *reinterpret_cast<const f16x8*>(&qbh[(size_t)(myq + 64) * D_K + 32 * p + 8 * lg]);
  }

  int4 sK0, sK1, sV0, sV1, sR0, sR1, sR2, sR3;
  auto GK = [&](int c0) {
    sK0 = *reinterpret_cast<const int4*>(gK0 + (size_t)c0 * D_K);
    sK1 = *reinterpret_cast<const int4*>(gK1 + (size_t)c0 * D_K);
  };
  auto GV = [&](int c0) {
    sV0 = *reinterpret_cast<const int4*>(gV0 + c0);
    sV1 = *reinterpret_cast<const int4*>(gV1 + c0);
  };
  auto GR = [&](int c0) {
    sR0 = *reinterpret_cast<const int4*>(gR0 + c0);
    sR1 = *reinterpret_cast<const int4*>(gR1 + c0);
    sR2 = *reinterpret_cast<const int4*>(gR2 + c0);
    sR3 = *reinterpret_cast<const int4*>(gR3 + c0);
  };
  auto DSW1 = [&](int bb) {  // K + rel (sweep 1)
    *reinterpret_cast<int4*>(&Kc[bb][dK0]) = sK0;
    *reinterpret_cast<int4*>(&Kc[bb][dK1]) = sK1;
    *reinterpret_cast<int4*>(&Rc[bb][dVR0]) = sR0;
    *reinterpret_cast<int4*>(&Rc[bb][dVR1]) = sR1;
    *reinterpret_cast<int4*>(&Rc[bb][dVR2]) = sR2;
    *reinterpret_cast<int4*>(&Rc[bb][dVR3]) = sR3;
  };
  auto DSW2 = [&](int bb) {  // K + V + rel (sweep 2)
    *reinterpret_cast<int4*>(&Kc[bb][dK0]) = sK0;
    *reinterpret_cast<int4*>(&Kc[bb][dK1]) = sK1;
    *reinterpret_cast<int4*>(&Vc[bb][dVR0]) = sV0;
    *reinterpret_cast<int4*>(&Vc[bb][dVR1]) = sV1;
    *reinterpret_cast<int4*>(&Rc[bb][dVR0]) = sR0;
    *reinterpret_cast<int4*>(&Rc[bb][dVR1]) = sR1;
    *reinterpret_cast<int4*>(&Rc[bb][dVR2]) = sR2;
    *reinterpret_cast<int4*>(&Rc[bb][dVR3]) = sR3;
  };

  auto SCORES = [&](int bb, const f16x8 (&qf8)[2], f32x4 (&sc)[4]) {
#pragma unroll
    for (int p = 0; p < 2; ++p) {
      const f16x4 qlo = __builtin_shufflevector(qf8[p], qf8[p], 0, 1, 2, 3);
      const f16x4 qhi = __builtin_shufflevector(qf8[p], qf8[p], 4, 5, 6, 7);
#pragma unroll
      for (int j = 0; j < 4; ++j) {
        const f16x8 kv = *reinterpret_cast<const f16x8*>(
            &Kc[bb][(16 * j + lr) * 64 + (((4 * p + lg) ^ lr7) << 3)]);
        sc[j] = __builtin_amdgcn_mfma_f32_16x16x16f16(
            __builtin_shufflevector(kv, kv, 0, 1, 2, 3), qlo, sc[j], 0, 0, 0);
        sc[j] = __builtin_amdgcn_mfma_f32_16x16x16f16(
            __builtin_shufflevector(kv, kv, 4, 5, 6, 7), qhi, sc[j], 0, 0, 0);
      }
    }
  };

  // ---- sweep 1: row sums for both tiles ----
  float sum0 = 0.f, sum1 = 0.f;
  GK(0);
  GR(0);
  DSW1(0);
  LBAR();
#pragma unroll 1
  for (int c = 0; c < 32; ++c) {
    if (c + 1 < 32) {
      GK((c + 1) * 64);
      GR((c + 1) * 64);
    }
    const int bb = c & 1;
    f32x4 sc0[4] = {}, sc1[4] = {};
    SCORES(bb, qf80, sc0);
    SCORES(bb, qf81, sc1);
#pragma unroll
    for (int j = 0; j < 4; ++j) {
      const int sgp = ((4 * j + lg) ^ (lr7 << 1)) & 15;
      const int col = c * 64 + 16 * j + 4 * lg;
      const f16x4 mh = *reinterpret_cast<const f16x4*>(&maskh[col]);
      const f16x4 rl0 = *reinterpret_cast<const f16x4*>(&Rc[bb][(w * 16 + lr) * 64 + (sgp << 2)]);
      const f16x4 rl1 = *reinterpret_cast<const f16x4*>(&Rc[bb][(w * 16 + lr + 64) * 64 + (sgp << 2)]);
      sum0 += __expf(sc0[j][0] + (float)rl0[0]) * (float)mh[0] +
              __expf(sc0[j][1] + (float)rl0[1]) * (float)mh[1] +
              __expf(sc0[j][2] + (float)rl0[2]) * (float)mh[2] +
              __expf(sc0[j][3] + (float)rl0[3]) * (float)mh[3];
      sum1 += __expf(sc1[j][0] + (float)rl1[0]) * (float)mh[0] +
              __expf(sc1[j][1] + (float)rl1[1]) * (float)mh[1] +
              __expf(sc1[j][2] + (float)rl1[2]) * (float)mh[2] +
              __expf(sc1[j][3] + (float)rl1[3]) * (float)mh[3];
    }
    if (c + 1 < 32) {
      DSW1((c + 1) & 1);
      LBAR();
    }
  }
  sum0 += __shfl_xor(sum0, 16, 64);
  sum0 += __shfl_xor(sum0, 32, 64);
  sum1 += __shfl_xor(sum1, 16, 64);
  sum1 += __shfl_xor(sum1, 32, 64);
  const float inv0 = 1.f / sum0;  // lane-local: q-row myq
  const float inv1 = 1.f / sum1;  // lane-local: q-row myq + 64

  // ---- sweep 2: normalized attn write + PV for both tiles ----
  f32x4 pv0[4] = {}, pv1[4] = {};
  GK(0);
  GV(0);
  GR(0);
  DSW2(0);   // writes buf0; waves still in sweep-1 c=31 only read buf1 -> safe
  LBAR();
#pragma unroll 1
  for (int c = 0; c < 32; ++c) {
    if (c + 1 < 32) {
      GK((c + 1) * 64);
      GV((c + 1) * 64);
      GR((c + 1) * 64);
    }
    const int bb = c & 1;
    f32x4 sc0[4] = {}, sc1[4] = {};
    SCORES(bb, qf80, sc0);
    SCORES(bb, qf81, sc1);
#pragma unroll
    for (int j = 0; j < 4; ++j) {
      const int sgp = ((4 * j + lg) ^ (lr7 << 1)) & 15;
      const int col = c * 64 + 16 * j + 4 * lg;
      const f16x4 mh = *reinterpret_cast<const f16x4*>(&maskh[col]);
      const f16x4 rl0 = *reinterpret_cast<const f16x4*>(&Rc[bb][(w * 16 + lr) * 64 + (sgp << 2)]);
      const f16x4 rl1 = *reinterpret_cast<const f16x4*>(&Rc[bb][(w * 16 + lr + 64) * 64 + (sgp << 2)]);
      const float a00 = __expf(sc0[j][0] + (float)rl0[0]) * (float)mh[0] * inv0;
      const float a01 = __expf(sc0[j][1] + (float)rl0[1]) * (float)mh[1] * inv0;
      const float a02 = __expf(sc0[j][2] + (float)rl0[2]) * (float)mh[2] * inv0;
      const float a03 = __expf(sc0[j][3] + (float)rl0[3]) * (float)mh[3] * inv0;
      const float a10 = __expf(sc1[j][0] + (float)rl1[0]) * (float)mh[0] * inv1;
      const float a11 = __expf(sc1[j][1] + (float)rl1[1]) * (float)mh[1] * inv1;
      const float a12 = __expf(sc1[j][2] + (float)rl1[2]) * (float)mh[2] * inv1;
      const float a13 = __expf(sc1[j][3] + (float)rl1[3]) * (float)mh[3] * inv1;
      f32x4 av0 = {a00, a01, a02, a03};
      f32x4 av1 = {a10, a11, a12, a13};
      __builtin_nontemporal_store(av0, reinterpret_cast<f32x4*>(&attnq0[col]));
      __builtin_nontemporal_store(av1, reinterpret_cast<f32x4*>(&attnq1[col]));
      f16x4 pf0, pf1;
      pf0.x = (f16)a00; pf0.y = (f16)a01; pf0.z = (f16)a02; pf0.w = (f16)a03;
      pf1.x = (f16)a10; pf1.y = (f16)a11; pf1.z = (f16)a12; pf1.w = (f16)a13;
#pragma unroll
      for (int nf = 0; nf < 4; ++nf) {
        const f16x4 vf = *reinterpret_cast<const f16x4*>(&Vc[bb][(nf * 16 + lr) * 64 + (sgp << 2)]);
        pv0[nf] = __builtin_amdgcn_mfma_f32_16x16x16f16(pf0, vf, pv0[nf], 0, 0, 0);
        pv1[nf] = __builtin_amdgcn_mfma_f32_16x16x16f16(pf1, vf, pv1[nf], 0, 0, 0);
      }
    }
    if (c + 1 < 32) {
      DSW2((c + 1) & 1);
      LBAR();
    }
  }

  // pv already normalized; D-layout rows r0+4lg+i (tile0) and +64 (tile1)
#pragma unroll
  for (int nf = 0; nf < 4; ++nf)
#pragma unroll
    for (int i = 0; i < 4; ++i) {
      ctx[(size_t)(b * S_LEN + r0 + 4 * lg + i) * D_MODEL + h * D_K + nf * 16 + lr] =
          (f16)pv0[nf][i];
      ctx[(size_t)(b * S_LEN + r0 + 64 + 4 * lg + i) * D_MODEL + h * D_K + nf * 16 + lr] =
          (f16)pv1[nf][i];
    }
}

// ---------------- fallback: single-pass, no staging, rel f32, attn written directly ----------------
__global__ __launch_bounds__(256) void attn_single(const f16* __restrict__ qg, const f16* __restrict__ kg,
                                                   const f16* __restrict__ vTg, const float* __restrict__ relp,
                                                   const int* __restrict__ mask, float* __restrict__ attn_out,
                                                   f16* __restrict__ ctx) {
  const int b = blockIdx.x & 3, qt = blockIdx.x >> 2;
  const int h = blockIdx.y;
  const int t = threadIdx.x, w = t >> 6, lane = t & 63;
  const int lr = lane & 15, lg = lane >> 4;
  __shared__ float mask_f[S_LEN];

  for (int i = t; i < S_LEN; i += 256) mask_f[i] = mask[b * S_LEN + i] ? EXP_NEG8 : 0.f;
  __syncthreads();

  const size_t bh = (size_t)(b * N_HEADS + h);
  const f16* qbh = qg + bh * S_LEN * D_K;
  const f16* kbh = kg + bh * S_LEN * D_K;
  const f16* vbh = vTg + bh * (size_t)D_K * S_LEN;

  const int r0 = qt * 64 + w * 16;
  const int myq = r0 + lr;

  const float* relq32 = relp + (size_t)h * S_LEN * S_LEN + (size_t)myq * S_LEN;
  float* attnq = attn_out + bh * (size_t)S_LEN * S_LEN + (size_t)myq * S_LEN;

  f16x8 qf8[2];
#pragma unroll
  for (int p = 0; p < 2; ++p)
    qf8[p] = *reinterpret_cast<const f16x8*>(&qbh[(size_t)myq * D_K + 32 * p + 8 * lg]);

  float sum = 0.f;
  f32x4 pv[4] = {};

  auto CH = [&](int c0) {
    f32x4 sc[4] = {};
#pragma unroll
    for (int p = 0; p < 2; ++p) {
      const f16x4 qlo = __builtin_shufflevector(qf8[p], qf8[p], 0, 1, 2, 3);
      const f16x4 qhi = __builtin_shufflevector(qf8[p], qf8[p], 4, 5, 6, 7);
#pragma unroll
      for (int j = 0; j < 4; ++j) {
        const f16x8 kv = *reinterpret_cast<const f16x8*>(
            &kbh[(size_t)(c0 + 16 * j + lr) * D_K + 32 * p + 8 * lg]);
        sc[j] = __builtin_amdgcn_mfma_f32_16x16x16f16(
            __builtin_shufflevector(kv, kv, 0, 1, 2, 3), qlo, sc[j], 0, 0, 0);
        sc[j] = __builtin_amdgcn_mfma_f32_16x16x16f16(
            __builtin_shufflevector(kv, kv, 4, 5, 6, 7), qhi, sc[j], 0, 0, 0);
      }
    }
#pragma unroll
    for (int j = 0; j < 4; ++j) {
      const int col = c0 + 16 * j + 4 * lg;
      const float4 rl = *reinterpret_cast<const float4*>(&relq32[col]);
      const float4 mk = *reinterpret_cast<const float4*>(&mask_f[col]);
      const float a0 = __expf(sc[j][0] + rl.x) * mk.x;
      const float a1 = __expf(sc[j][1] + rl.y) * mk.y;
      const float a2 = __expf(sc[j][2] + rl.z) * mk.z;
      const float a3 = __expf(sc[j][3] + rl.w) * mk.w;
      sum += a0 + a1 + a2 + a3;
      f16x4 pf;
      pf.x = (f16)a0; pf.y = (f16)a1; pf.z = (f16)a2; pf.w = (f16)a3;
      *reinterpret_cast<float4*>(&attnq[col]) = make_float4(a0, a1, a2, a3);
#pragma unroll
      for (int nf = 0; nf < 4; ++nf) {
        const f16x4 vf = *reinterpret_cast<const f16x4*>(&vbh[(size_t)(nf * 16 + lr) * S_LEN + col]);
        pv[nf] = __builtin_amdgcn_mfma_f32_16x16x16f16(pf, vf, pv[nf], 0, 0, 0);
      }
    }
  };

#pragma unroll 1
  for (int c0 = 0; c0 < S_LEN; c0 += 64) CH(c0);

  sum += __shfl_xor(sum, 16, 64);
  sum += __shfl_xor(sum, 32, 64);
  const float inv = 1.f / sum;

  float ivr[4];
#pragma unroll
  for (int i = 0; i < 4; ++i) ivr[i] = __shfl(inv, 4 * lg + i, 64);
#pragma unroll
  for (int nf = 0; nf < 4; ++nf)
#pragma unroll
    for (int i = 0; i < 4; ++i)
      ctx[(size_t)(b * S_LEN + r0 + 4 * lg + i) * D_MODEL + h * D_K + nf * 16 + lr] =
          (f16)(pv[nf][i] * ivr[i]);

  float4* aw4 = reinterpret_cast<float4*>(attn_out + bh * (size_t)S_LEN * S_LEN + (size_t)r0 * S_LEN);
#pragma unroll 1
  for (int it = 0; it < 128; it += 4) {
#pragma unroll
    for (int u = 0; u < 4; ++u) {
      const float iv = __shfl(inv, (it + u) >> 3, 64);
      float4 v = aw4[(it + u) * 64 + lane];
      v.x *= iv; v.y *= iv; v.z *= iv; v.w *= iv;
      aw4[(it + u) * 64 + lane] = v;
    }
  }
}

extern "C" void kernel_launch(void* const* d_in, const int* in_sizes, int n_in,
                              void* d_out, int out_size, void* d_ws, size_t ws_size,
                              hipStream_t stream) {
  const float* Q    = (const float*)d_in[0];
  const float* K    = (const float*)d_in[1];
  const float* V    = (const float*)d_in[2];
  const int*   mask = (const int*)d_in[3];
  const float* rel  = (const float*)d_in[4];
  const float* Wq   = (const float*)d_in[5];
  const float* bq   = (const float*)d_in[6];
  const float* Wk   = (const float*)d_in[7];
  const float* bk   = (const float*)d_in[8];
  const float* Wv   = (const float*)d_in[9];
  const float* bv   = (const float*)d_in[10];
  const float* Wo   = (const float*)d_in[11];
  const float* bo   = (const float*)d_in[12];

  char* wsb = (char*)d_ws;
  const size_t XSZ = (size_t)BATCH * S_LEN * D_MODEL * sizeof(f16);  // 16.78 MB
  const size_t WSZ = (size_t)D_MODEL * D_MODEL * sizeof(f16);        // 2 MB
  f16* Qh  = (f16*)(wsb);
  f16* Kh  = (f16*)(wsb + XSZ);
  f16* Vh  = (f16*)(wsb + 2 * XSZ);
  f16* WqT = (f16*)(wsb + 3 * XSZ);
  f16* WkT = (f16*)(wsb + 3 * XSZ + WSZ);
  f16* WvT = (f16*)(wsb + 3 * XSZ + 2 * WSZ);
  f16* WoT = (f16*)(wsb + 3 * XSZ + 3 * WSZ);
  f16* qb  = (f16*)(wsb + 3 * XSZ + 4 * WSZ);
  f16* kb  = (f16*)(wsb + 4 * XSZ + 4 * WSZ);
  f16* vTb = (f16*)(wsb + 5 * XSZ + 4 * WSZ);
  f16* ctx = (f16*)(wsb + 6 * XSZ + 4 * WSZ);

  const size_t BASE  = 7 * XSZ + 4 * WSZ;                                 // 125.8 MB
  const size_t RELSZ = (size_t)N_HEADS * S_LEN * S_LEN * sizeof(f16);     // 134.2 MB
  f16* rel16 = (f16*)(wsb + BASE);
  const bool r16 = ws_size >= BASE + RELSZ;

  float* out0 = (float*)d_out;
  float* attn = out0 + (size_t)BATCH * S_LEN * D_MODEL;

  const int n4 = BATCH * S_LEN * D_MODEL / 4;  // 2097152
  cvt3<<<dim3(n4 / 256, 3), 256, 0, stream>>>(Q, K, V, Qh, Kh, Vh, n4);
  wtrans4<<<dim3(32, 32, 4), dim3(32, 8), 0, stream>>>(Wq, Wk, Wv, Wo, WqT, WkT, WvT, WoT);
  if (r16) {
    const int nr4 = N_HEADS * S_LEN * S_LEN / 4;  // 16,777,216
    cvt_f32_f16<<<dim3(nr4 / 256), 256, 0, stream>>>(rel, rel16, nr4);
  }

  gemmQKV<<<dim3(8, 64, 3), 256, 0, stream>>>(Qh, Kh, Vh, WqT, WkT, WvT, bq, bk, bv, qb, kb, vTb);

  if (r16) {
    attn_fused2<<<dim3(BATCH * (S_LEN / 128), N_HEADS), 256, 0, stream>>>(qb, kb, vTb, rel16, mask,
                                                                          attn, ctx);
  } else {
    attn_single<<<dim3(BATCH * (S_LEN / 64), N_HEADS), 256, 0, stream>>>(qb, kb, vTb, rel, mask,
                                                                         attn, ctx);
  }

  gemmO<<<dim3(8, 64), 256, 0, stream>>>(ctx, WoT, bo, out0);
}